// Round 3
// baseline (1098.652 us; speedup 1.0000x reference)
//
#include <hip/hip_runtime.h>
#include <math.h>
#include <float.h>

// ResidualVectorQuantizer — Round 6: occupancy (drop Af, 4 blocks/CU), revert qacc.
//
// np ref model (verified exact, absmax 0 in R2/R3/R5b):
//   G = r @ W.T (sequential-k fmaf), dist = fl(fl(sq_r+sq_w) - fl(2G)),
//   idx = lex-(dist,k) argmin; sq_r/sq_w = numpy pairwise sum (128+128, 8 acc).
// Stage 1 ranks with fp16 MFMA; |np_dist - approx| <= MARGIN; the within-margin
// candidate set is collected exactly and rescored with the exact np formula.
//
// R6 changes:
//  * Af (16 KB fp16 fragment mirror of resS) removed; A-fragments are built at
//    ph2 entry from resS f32 (same single f32->f16 rounding => bit-identical).
//    LDS 50 KB -> 34.4 KB => 4 blocks/CU (was 3). Barrier-overlap +33%.
//  * qacc register carry reverted (R5b: VGPR stayed 84 => it was spilled and
//    ph6 got slower). Back to q round-trip via out (write every level, read
//    c>=1), but rv still comes from resS (verified bit-exact, saves x reads).
//  * nt hints on x / out-q streams (never-reused lines; protect cb+bws in L2).

#define N_ROWS 65536
#define DIM    256
#define K_NUM  1024
#define N_CB   4
#define RPB    32
#define QOFF   16777216     // N_ROWS*DIM
#define IDXOFF 16777219     // QOFF + 3 scalars
#define NPAIRS 523776
#define MARGIN 2.4e-4f

#define SWZV(row, dunit) ((row) * DIM + ((((dunit) ^ ((row) & 7))) << 1))
#define SWZ2(row, d)     ((row) * DIM + ((((((d) >> 1) ^ ((row) & 7))) << 1) | ((d) & 1)))

typedef _Float16 f16x8 __attribute__((ext_vector_type(8)));
typedef float    f32x4 __attribute__((ext_vector_type(4)));

// ---------------- ws layout ----------------
// [0, 32768)        double wn64[4096]      (fallback pdist only)
// [32768, 49152)    float  sqw[4096]       (np-exact ||w||^2)
// [49152, 65536)    int    counts[4096]
// [65536, 65568)    double sse[4]
// [65568, 65576)    double pdacc[1]
// [69632, 2166784)  _Float16 bws[1048576]  (fp16 codebooks, fragment-major)
#define WS_BWS_OFF 69632
#define WS_NEEDED  2166784

__device__ __forceinline__ bool lexless(float a, int ka, float b, int kb) {
  return (a < b) || (a == b && ka < kb);
}

__global__ void zero_ws(int* counts, double* sse, double* pdacc) {
  int t = blockIdx.x * blockDim.x + threadIdx.x;
  if (t < 4096) counts[t] = 0;
  if (t < 4) sse[t] = 0.0;
  if (t == 0) pdacc[0] = 0.0;
}

// np-exact sum(W*W, axis=1): pairwise structure for n=256
__global__ void np_sqw_kernel(const float* __restrict__ cb,
                              float* __restrict__ sqw) {
#pragma clang fp contract(off)
  int g = blockIdx.x * blockDim.x + threadIdx.x;  // 0..4095
  const float* row = cb + (size_t)g * DIM;
  float blk[2];
#pragma unroll
  for (int b = 0; b < 2; ++b) {
    const float* a = row + b * 128;
    float r[8];
#pragma unroll
    for (int j = 0; j < 8; ++j) { float v = a[j]; r[j] = v * v; }
    for (int i = 8; i < 128; i += 8) {
#pragma unroll
      for (int j = 0; j < 8; ++j) { float v = a[i + j]; r[j] = r[j] + v * v; }
    }
    blk[b] = ((r[0] + r[1]) + (r[2] + r[3])) + ((r[4] + r[5]) + (r[6] + r[7]));
  }
  sqw[g] = blk[0] + blk[1];
}

// codebooks -> fp16 fragment-major (global layout is linear, lane*8)
__global__ void cvt_b_kernel(const float* __restrict__ cb,
                             _Float16* __restrict__ bws) {
  int tg = blockIdx.x * blockDim.x + threadIdx.x;  // 131072 threads
  int row = tg >> 5;        // 0..4095
  int chunk = tg & 31;
  int c = row >> 10, n = row & 1023;
  int nt = n >> 4, nin = n & 15;
  int kk = chunk >> 2, quad = chunk & 3;
  const float* src = cb + (size_t)row * DIM + chunk * 8;
  f16x8 h;
#pragma unroll
  for (int j = 0; j < 8; ++j) h[j] = (_Float16)src[j];
  size_t dst = ((size_t)((c * 64 + nt) * 8 + kk) * 64 + quad * 16 + nin) * 8;
  *(f16x8*)(bws + dst) = h;
}

// all-pairs mean distance via fp16 MFMA Gram (precision irrelevant: thr 20.48)
__global__ __launch_bounds__(256) void pdist_mfma(
    const _Float16* __restrict__ bws, const float* __restrict__ sqw,
    double* __restrict__ pdacc) {
  int t = threadIdx.x, lane = t & 63, wq = t >> 6;
  int quad = lane >> 4, col = lane & 15;
  int c = blockIdx.x >> 6, iT = blockIdx.x & 63;
  const float* sq = sqw + c * K_NUM;
  const _Float16* base = bws + ((size_t)(c * 64) * 8) * 512 + lane * 8;
  f16x8 Ar[8];
#pragma unroll
  for (int kk = 0; kk < 8; ++kk)
    Ar[kk] = *(const f16x8*)(base + (size_t)(iT * 8 + kk) * 512);
  float bi[4];
#pragma unroll
  for (int r = 0; r < 4; ++r) bi[r] = sq[iT * 16 + quad * 4 + r];
  float sum = 0.f;
#pragma unroll 1
  for (int jt0 = 0; jt0 < 16; ++jt0) {
    int jt = wq * 16 + jt0;
    f16x8 Br[8];
#pragma unroll
    for (int kk = 0; kk < 8; ++kk)
      Br[kk] = *(const f16x8*)(base + (size_t)(jt * 8 + kk) * 512);
    f32x4 acc = {0.f, 0.f, 0.f, 0.f};
#pragma unroll
    for (int kk = 0; kk < 8; ++kk)
      acc = __builtin_amdgcn_mfma_f32_16x16x32_f16(Ar[kk], Br[kk], acc, 0, 0, 0);
    int j = jt * 16 + col;
    float bj = sq[j];
#pragma unroll
    for (int r = 0; r < 4; ++r) {
      int i = iT * 16 + quad * 4 + r;
      float d2 = bi[r] + bj - 2.0f * acc[r];
      if (i != j) sum += sqrtf(fmaxf(d2, 0.f));
    }
  }
  double ds = (double)sum;
#pragma unroll
  for (int off = 32; off; off >>= 1) ds += __shfl_xor(ds, off, 64);
  if (lane == 0) atomicAdd(pdacc, ds);
}

// ================= MFMA main kernel =================
__global__ __launch_bounds__(256, 4) void rvq_main_mfma(
    const float* __restrict__ x, const float* __restrict__ cb,
    const _Float16* __restrict__ bws, const float* __restrict__ sqw,
    int* __restrict__ counts, double* __restrict__ sse,
    float* __restrict__ out) {
  __shared__ float resS[RPB * DIM];                      // 32 KB, swizzled f32
  __shared__ float wminS[RPB * 4];
  __shared__ int hardCnt[RPB];
  __shared__ int hardIdx[RPB * 6];
  __shared__ int idxS[RPB];
  __shared__ float sqrS[RPB];

  int t = threadIdx.x;            // 0..255
  int lane = t & 63, wq = t >> 6;
  int quad = lane >> 4, m16 = lane & 15;
  int rb = blockIdx.x * RPB;
  int dchunk = t & 31, rowgrp = t >> 5;   // update/staging mapping (8d chunks)

  // ---- stage: residual = x -> resS (f32) ----
#pragma unroll
  for (int i = 0; i < 4; ++i) {
    int row = rowgrp * 4 + i;
    size_t go = (size_t)(rb + row) * DIM + dchunk * 8;
    f32x4 v0 = __builtin_nontemporal_load((const f32x4*)&x[go]);
    f32x4 v1 = __builtin_nontemporal_load((const f32x4*)&x[go + 4]);
    int u0 = dchunk * 4;
    *(float2*)&resS[SWZV(row, u0 + 0)] = make_float2(v0[0], v0[1]);
    *(float2*)&resS[SWZV(row, u0 + 1)] = make_float2(v0[2], v0[3]);
    *(float2*)&resS[SWZV(row, u0 + 2)] = make_float2(v1[0], v1[1]);
    *(float2*)&resS[SWZV(row, u0 + 3)] = make_float2(v1[2], v1[3]);
  }
  __syncthreads();

  for (int c = 0; c < N_CB; ++c) {
    const float* cbl = cb + (size_t)c * K_NUM * DIM;
    const float* sqwl = sqw + c * K_NUM;

    // ---- ph0: np-exact sq_r per row (8-lane pairwise replica) ----
    {
#pragma clang fp contract(off)
      int kg = t & 7, rg = t >> 3;
      float blk[2];
#pragma unroll
      for (int b = 0; b < 2; ++b) {
        float v0 = resS[SWZ2(rg, b * 128 + kg)];
        float acc = v0 * v0;
        for (int i = 1; i < 16; ++i) {
          float v = resS[SWZ2(rg, b * 128 + kg + 8 * i)];
          acc = acc + v * v;
        }
        acc = acc + __shfl_xor(acc, 1, 8);
        acc = acc + __shfl_xor(acc, 2, 8);
        acc = acc + __shfl_xor(acc, 4, 8);
        blk[b] = acc;
      }
      if (kg == 0) sqrS[rg] = blk[0] + blk[1];
    }

    // ---- ph2: MFMA scoring; A-frags rebuilt from resS f32 (bit-identical
    //      single f32->f16 rounding), B streamed from L2 ----
    f16x8 Ar[2][8];
#pragma unroll
    for (int mt = 0; mt < 2; ++mt) {
      int arow = mt * 16 + m16;
#pragma unroll
      for (int kk = 0; kk < 8; ++kk) {
        f16x8 h;
#pragma unroll
        for (int jj = 0; jj < 4; ++jj) {
          float2 p = *(const float2*)&resS[SWZV(arow, kk * 16 + quad * 4 + jj)];
          h[2 * jj]     = (_Float16)p.x;
          h[2 * jj + 1] = (_Float16)p.y;
        }
        Ar[mt][kk] = h;
      }
    }
    float s1[2][4], s2[2][4]; int k1[2][4], k2[2][4];
#pragma unroll
    for (int mt = 0; mt < 2; ++mt)
#pragma unroll
      for (int r = 0; r < 4; ++r) {
        s1[mt][r] = FLT_MAX; s2[mt][r] = FLT_MAX;
        k1[mt][r] = 0x7FFFFFFF; k2[mt][r] = 0x7FFFFFFF;
      }
    const _Float16* Bc = bws + (size_t)((c * 64 + wq * 16) * 8) * 512 + lane * 8;
#pragma unroll 1
    for (int nt = 0; nt < 16; ++nt) {
      const _Float16* Bp = Bc + (size_t)nt * 8 * 512;
      f16x8 Br[8];
#pragma unroll
      for (int kk = 0; kk < 8; ++kk)
        Br[kk] = *(const f16x8*)(Bp + (size_t)kk * 512);
      f32x4 acc0 = {0.f, 0.f, 0.f, 0.f}, acc1 = {0.f, 0.f, 0.f, 0.f};
#pragma unroll
      for (int kk = 0; kk < 8; ++kk) {
        acc0 = __builtin_amdgcn_mfma_f32_16x16x32_f16(Ar[0][kk], Br[kk], acc0, 0, 0, 0);
        acc1 = __builtin_amdgcn_mfma_f32_16x16x32_f16(Ar[1][kk], Br[kk], acc1, 0, 0, 0);
      }
      int n = (wq * 16 + nt) * 16 + m16;
      float w2 = sqwl[n];
#pragma unroll
      for (int r = 0; r < 4; ++r) {
        float sa = w2 - 2.0f * acc0[r];
        if (sa < s1[0][r]) { s2[0][r] = s1[0][r]; k2[0][r] = k1[0][r]; s1[0][r] = sa; k1[0][r] = n; }
        else if (sa < s2[0][r]) { s2[0][r] = sa; k2[0][r] = n; }
        float sb = w2 - 2.0f * acc1[r];
        if (sb < s1[1][r]) { s2[1][r] = s1[1][r]; k2[1][r] = k1[1][r]; s1[1][r] = sb; k1[1][r] = n; }
        else if (sb < s2[1][r]) { s2[1][r] = sb; k2[1][r] = n; }
      }
    }

    // ---- step1: per-wave row-min -> wminS; zero hardCnt ----
    if (t < RPB) hardCnt[t] = 0;
#pragma unroll
    for (int mt = 0; mt < 2; ++mt)
#pragma unroll
      for (int r = 0; r < 4; ++r) {
        float mn = s1[mt][r];
#pragma unroll
        for (int off = 1; off <= 8; off <<= 1)
          mn = fminf(mn, __shfl_xor(mn, off, 16));
        if (m16 == 0) wminS[(mt * 16 + quad * 4 + r) * 4 + wq] = mn;
      }
    __syncthreads();

    // ---- step2: global thr; collect within-margin candidates via LDS atomics
#pragma unroll
    for (int mt = 0; mt < 2; ++mt)
#pragma unroll
      for (int r = 0; r < 4; ++r) {
        int row = mt * 16 + quad * 4 + r;
        float thr = fminf(fminf(wminS[row * 4 + 0], wminS[row * 4 + 1]),
                          fminf(wminS[row * 4 + 2], wminS[row * 4 + 3])) + MARGIN;
        bool c1 = s1[mt][r] <= thr;
        if (c1) {
          bool c2 = s2[mt][r] <= thr;
          int pos = atomicAdd(&hardCnt[row], 1 + (c2 ? 1 : 0));
          if (pos < 6) hardIdx[row * 6 + pos] = k1[mt][r];
          if (c2 && pos + 1 < 6) hardIdx[row * 6 + pos + 1] = k2[mt][r];
        }
      }
    __syncthreads();

    // ---- ph5: winner per row (cnt==1 fast; else exact np rescore) ----
    {
      int kg = t & 7, rg = t >> 3;
      int cnt = hardCnt[rg]; if (cnt > 6) cnt = 6;
      int winner;
      if (cnt == 1) {
        winner = hardIdx[rg * 6];
      } else {
        float myd = FLT_MAX; int myk = 0x7FFFFFFF;
        if (kg < cnt) {
          int k = hardIdx[rg * 6 + kg];
          const float* wrow = cbl + (size_t)k * DIM;
          float gsum = 0.0f;
#pragma unroll 8
          for (int d = 0; d < DIM; ++d)
            gsum = __builtin_fmaf(wrow[d], resS[SWZ2(rg, d)], gsum);
          float T = sqrS[rg] + sqwl[k];   // fl(sq_r + sq_w)
          myd = T - 2.0f * gsum;          // fl(T - 2g), 2g exact
          myk = k;
        }
#pragma unroll
        for (int off = 1; off <= 4; off <<= 1) {
          float od = __shfl_xor(myd, off, 8);
          int   ok = __shfl_xor(myk, off, 8);
          if (lexless(od, ok, myd, myk)) { myd = od; myk = ok; }
        }
        winner = myk;
      }
      if (kg == 0) {
        idxS[rg] = winner;
        out[(size_t)IDXOFF + (size_t)c * N_ROWS + rb + rg] = (float)winner;
        atomicAdd(&counts[c * K_NUM + winner], 1);
      }
    }
    __syncthreads();

    // ---- ph6: exact f32 update chain (rv from resS, q round-trip via out) --
    // per-elem chain (verified exact): rv == fl(x - q_prev) (stored resS)
    //   e = wv - rv; qs = rv + e; qn = q_prev + qs; rn = fl(x - qn)
    double lsse = 0.0;
#pragma unroll
    for (int i = 0; i < 4; ++i) {
      int row = rowgrp * 4 + i;
      int widx = idxS[row];
      size_t go = (size_t)(rb + row) * DIM + dchunk * 8;
      float wv[8], rv[8], xv[8], qv[8];
      const float* wrow = cbl + (size_t)widx * DIM + dchunk * 8;
      *(float4*)&wv[0] = *(const float4*)&wrow[0];
      *(float4*)&wv[4] = *(const float4*)&wrow[4];
      int u0 = dchunk * 4;
      *(float2*)&rv[0] = *(const float2*)&resS[SWZV(row, u0 + 0)];
      *(float2*)&rv[2] = *(const float2*)&resS[SWZV(row, u0 + 1)];
      *(float2*)&rv[4] = *(const float2*)&resS[SWZV(row, u0 + 2)];
      *(float2*)&rv[6] = *(const float2*)&resS[SWZV(row, u0 + 3)];
      if (c != 0) {
        f32x4 qa = __builtin_nontemporal_load((const f32x4*)&out[go]);
        f32x4 qb = __builtin_nontemporal_load((const f32x4*)&out[go + 4]);
#pragma unroll
        for (int j = 0; j < 4; ++j) { qv[j] = qa[j]; qv[4 + j] = qb[j]; }
      }
      if (c == 1 || c == 2) {   // levels needing rn = fl(x - qn) with global x
        f32x4 xa = __builtin_nontemporal_load((const f32x4*)&x[go]);
        f32x4 xb = __builtin_nontemporal_load((const f32x4*)&x[go + 4]);
#pragma unroll
        for (int j = 0; j < 4; ++j) { xv[j] = xa[j]; xv[4 + j] = xb[j]; }
      }
      float rnv[8];
      f32x4 o0, o1;
#pragma unroll
      for (int j = 0; j < 8; ++j) {
        float e = wv[j] - rv[j];                       // e = q - r
        float qs = rv[j] + e;                          // q_st
        float qn = (c == 0) ? qs : (qv[j] + qs);       // quantized accum
        if (j < 4) o0[j] = qn; else o1[j - 4] = qn;
        lsse += (double)e * (double)e;
        if (c < N_CB - 1) {
          // c==0: x == rv (resS held x), bit-exact; c==1,2: x from global
          rnv[j] = (c == 0) ? (rv[j] - qn) : (xv[j] - qn);
        }
      }
      __builtin_nontemporal_store(o0, (f32x4*)&out[go]);
      __builtin_nontemporal_store(o1, (f32x4*)&out[go + 4]);
      if (c < N_CB - 1) {
        *(float2*)&resS[SWZV(row, u0 + 0)] = make_float2(rnv[0], rnv[1]);
        *(float2*)&resS[SWZV(row, u0 + 1)] = make_float2(rnv[2], rnv[3]);
        *(float2*)&resS[SWZV(row, u0 + 2)] = make_float2(rnv[4], rnv[5]);
        *(float2*)&resS[SWZV(row, u0 + 3)] = make_float2(rnv[6], rnv[7]);
      }
    }
#pragma unroll
    for (int off = 32; off; off >>= 1) lsse += __shfl_xor(lsse, off, 64);
    if ((t & 63) == 0) atomicAdd(&sse[c], lsse);
    __syncthreads();
  }  // levels
}

// ================= fallback path (small ws): R2 VALU kernels ================
__global__ void wnorm_kernel(const float* __restrict__ cb,
                             double* __restrict__ wn64) {
  int gw = blockIdx.x * 4 + (threadIdx.x >> 6);
  int lane = threadIdx.x & 63;
  const float* row = cb + (size_t)gw * DIM;
  float4 v = *(const float4*)(row + lane * 4);
  double s = (double)v.x * v.x + (double)v.y * v.y +
             (double)v.z * v.z + (double)v.w * v.w;
#pragma unroll
  for (int off = 32; off; off >>= 1) s += __shfl_xor(s, off, 64);
  if (lane == 0) wn64[gw] = s;
}

__global__ void pdist_kernel(const float* __restrict__ cb,
                             const double* __restrict__ wn64,
                             double* __restrict__ pdacc) {
  __shared__ float wi[DIM];
  int c = blockIdx.x >> 10;
  int i = blockIdx.x & 1023;
  int t = threadIdx.x;  // 128
  const float* rowi = cb + ((size_t)c * K_NUM + i) * DIM;
  *(float2*)&wi[t * 2] = *(const float2*)&rowi[t * 2];
  __syncthreads();
  double bi = wn64[c * K_NUM + i];
  double lsum = 0.0;
  for (int j = i + 1 + t; j < K_NUM; j += 128) {
    const float* rowj = cb + ((size_t)c * K_NUM + j) * DIM;
    double dot = 0.0;
#pragma unroll 8
    for (int d = 0; d < DIM; ++d) dot += (double)rowj[d] * (double)wi[d];
    double d2 = bi + wn64[c * K_NUM + j] - 2.0 * dot;
    lsum += sqrt(fmax(d2, 0.0));
  }
#pragma unroll
  for (int off = 32; off; off >>= 1) lsum += __shfl_xor(lsum, off, 64);
  if ((t & 63) == 0) atomicAdd(pdacc, lsum);
}

__global__ __launch_bounds__(128) void rvq_main_fb(
    const float* __restrict__ x, const float* __restrict__ cb,
    const float* __restrict__ sqw,
    int* __restrict__ counts, double* __restrict__ sse,
    float* __restrict__ out) {
  __shared__ float Wt[RPB * DIM];
  __shared__ float resS[RPB * DIM];
  int t = threadIdx.x;
  int kg = t & 7;
  int rg = t >> 3;
  int rb = blockIdx.x * RPB;
#pragma unroll 4
  for (int it = 0; it < RPB; ++it) {
    float2 v = *(const float2*)&x[(size_t)(rb + it) * DIM + t * 2];
    *(float2*)&resS[SWZV(it, t)] = v;
  }
  __syncthreads();
  for (int c = 0; c < N_CB; ++c) {
    const float* cbl = cb + (size_t)c * K_NUM * DIM;
    const float* sqwl = sqw + c * K_NUM;
    float sqr[2];
    {
#pragma clang fp contract(off)
#pragma unroll
      for (int j = 0; j < 2; ++j) {
        int row = rg + 16 * j;
        float blk[2];
#pragma unroll
        for (int b = 0; b < 2; ++b) {
          float v0 = resS[SWZ2(row, b * 128 + kg)];
          float acc = v0 * v0;
          for (int i = 1; i < 16; ++i) {
            float v = resS[SWZ2(row, b * 128 + kg + 8 * i)];
            acc = acc + v * v;
          }
          acc = acc + __shfl_xor(acc, 1, 8);
          acc = acc + __shfl_xor(acc, 2, 8);
          acc = acc + __shfl_xor(acc, 4, 8);
          blk[b] = acc;
        }
        sqr[j] = blk[0] + blk[1];
      }
    }
    float m1[2], m2[2]; int i1[2], i2[2];
    m1[0] = m1[1] = m2[0] = m2[1] = FLT_MAX;
    i1[0] = i1[1] = i2[0] = i2[1] = 0x7FFFFFFF;
    for (int tile = 0; tile < K_NUM / 32; ++tile) {
      __syncthreads();
      const float* wsrc = cbl + (size_t)tile * 32 * DIM;
#pragma unroll 4
      for (int it = 0; it < 32; ++it) {
        float2 v = *(const float2*)&wsrc[(size_t)it * DIM + t * 2];
        *(float2*)&Wt[SWZV(it, t)] = v;
      }
      __syncthreads();
      float acc[4][2] = {{0.f, 0.f}, {0.f, 0.f}, {0.f, 0.f}, {0.f, 0.f}};
#pragma unroll 8
      for (int du = 0; du < DIM / 2; ++du) {
        float2 r0 = *(const float2*)&resS[SWZV(rg, du)];
        float2 r1 = *(const float2*)&resS[SWZV(rg + 16, du)];
#pragma unroll
        for (int i = 0; i < 4; ++i) {
          int k = kg + 8 * i;
          float2 w = *(const float2*)&Wt[SWZV(k, du)];
          acc[i][0] += w.x * r0.x; acc[i][0] += w.y * r0.y;
          acc[i][1] += w.x * r1.x; acc[i][1] += w.y * r1.y;
        }
      }
#pragma unroll
      for (int i = 0; i < 4; ++i) {
        int k = tile * 32 + kg + 8 * i;
        float b = sqwl[k];
#pragma unroll
        for (int j = 0; j < 2; ++j) {
          float s = b - 2.0f * acc[i][j];
          if (lexless(s, k, m1[j], i1[j])) {
            m2[j] = m1[j]; i2[j] = i1[j]; m1[j] = s; i1[j] = k;
          } else if (lexless(s, k, m2[j], i2[j])) {
            m2[j] = s; i2[j] = k;
          }
        }
      }
    }
    float as[2][4]; int ak[2][4];
#pragma unroll
    for (int j = 0; j < 2; ++j) {
      as[j][0] = m1[j]; ak[j][0] = i1[j];
      as[j][1] = m2[j]; ak[j][1] = i2[j];
      as[j][2] = FLT_MAX; ak[j][2] = 0x7FFFFFFF;
      as[j][3] = FLT_MAX; ak[j][3] = 0x7FFFFFFF;
#pragma unroll
      for (int off = 1; off <= 4; off <<= 1) {
        float bs[4]; int bk[4];
#pragma unroll
        for (int q = 0; q < 4; ++q) {
          bs[q] = __shfl_xor(as[j][q], off, 8);
          bk[q] = __shfl_xor(ak[j][q], off, 8);
        }
        float cs[4]; int ck[4];
#pragma unroll
        for (int q = 0; q < 4; ++q) {
          bool ta = lexless(as[j][q], ak[j][q], bs[3 - q], bk[3 - q]);
          cs[q] = ta ? as[j][q] : bs[3 - q];
          ck[q] = ta ? ak[j][q] : bk[3 - q];
        }
#define CE(p, q) { bool sw = lexless(cs[q], ck[q], cs[p], ck[p]); \
                   float ts = sw ? cs[q] : cs[p]; int tk = sw ? ck[q] : ck[p]; \
                   cs[q] = sw ? cs[p] : cs[q]; ck[q] = sw ? ck[p] : ck[q]; \
                   cs[p] = ts; ck[p] = tk; }
        CE(0, 2) CE(1, 3) CE(0, 1) CE(2, 3)
#undef CE
#pragma unroll
        for (int q = 0; q < 4; ++q) { as[j][q] = cs[q]; ak[j][q] = ck[q]; }
      }
    }
    int winner[2];
#pragma unroll
    for (int j = 0; j < 2; ++j) {
      if (as[j][1] <= as[j][0] + 1.2e-4f) {
        int row = rg + 16 * j;
        float ss = (kg == 0) ? as[j][0] : (kg == 1) ? as[j][1]
                 : (kg == 2) ? as[j][2] : (kg == 3) ? as[j][3] : FLT_MAX;
        int   sk = (kg == 0) ? ak[j][0] : (kg == 1) ? ak[j][1]
                 : (kg == 2) ? ak[j][2] : (kg == 3) ? ak[j][3] : 0x7FFFFFFF;
        float myd = FLT_MAX; int myk = 0x7FFFFFFF;
        if (kg < 4 && ss <= as[j][0] + 1.2e-4f) {
          const float* wrow = cbl + (size_t)sk * DIM;
          float g = 0.0f;
#pragma unroll 8
          for (int d = 0; d < DIM; ++d)
            g = __builtin_fmaf(wrow[d], resS[SWZ2(row, d)], g);
          float T = sqr[j] + sqwl[sk];
          myd = T - 2.0f * g;
          myk = sk;
        }
#pragma unroll
        for (int off = 1; off <= 4; off <<= 1) {
          float od = __shfl_xor(myd, off, 8);
          int   ok = __shfl_xor(myk, off, 8);
          if (lexless(od, ok, myd, myk)) { myd = od; myk = ok; }
        }
        winner[j] = myk;
      } else {
        winner[j] = ak[j][0];
      }
    }
    __syncthreads();
    int* idxSf = (int*)Wt;
    if (kg == 0) {
      idxSf[rg] = winner[0];
      idxSf[rg + 16] = winner[1];
      out[(size_t)IDXOFF + (size_t)c * N_ROWS + rb + rg] = (float)winner[0];
      out[(size_t)IDXOFF + (size_t)c * N_ROWS + rb + rg + 16] = (float)winner[1];
      atomicAdd(&counts[c * K_NUM + winner[0]], 1);
      atomicAdd(&counts[c * K_NUM + winner[1]], 1);
    }
    __syncthreads();
    double lsse = 0.0;
#pragma unroll 4
    for (int it = 0; it < RPB; ++it) {
      int widx = idxSf[it];
      size_t go = (size_t)(rb + it) * DIM + t * 2;
      float2 wv = *(const float2*)&cbl[(size_t)widx * DIM + t * 2];
      float2 rv = *(const float2*)&resS[SWZV(it, t)];
      float ex = wv.x - rv.x, ey = wv.y - rv.y;
      float qsx = rv.x + ex, qsy = rv.y + ey;
      float qnx, qny;
      if (c == 0) { qnx = qsx; qny = qsy; }
      else { float2 qo = *(const float2*)&out[go]; qnx = qo.x + qsx; qny = qo.y + qsy; }
      *(float2*)&out[go] = make_float2(qnx, qny);
      float2 xv = *(const float2*)&x[go];
      float rnx = xv.x - qnx, rny = xv.y - qny;
      *(float2*)&resS[SWZV(it, t)] = make_float2(rnx, rny);
      lsse += (double)ex * (double)ex + (double)ey * (double)ey;
    }
#pragma unroll
    for (int off = 32; off; off >>= 1) lsse += __shfl_xor(lsse, off, 64);
    if ((t & 63) == 0) atomicAdd(&sse[c], lsse);
    __syncthreads();
  }
}

__global__ void finalize_kernel(const int* __restrict__ counts,
                                const double* __restrict__ sse,
                                const double* __restrict__ pdacc,
                                float* __restrict__ out, double pdscale) {
  __shared__ double red[1024];
  int t = threadIdx.x;
  double u = 0.0;
#pragma unroll
  for (int c = 0; c < 4; ++c) u += fabs((double)counts[c * 1024 + t] - 64.0);
  red[t] = u;
  __syncthreads();
  for (int s = 512; s; s >>= 1) {
    if (t < s) red[t] += red[t + s];
    __syncthreads();
  }
  if (t == 0) {
    double q = 0.0;
#pragma unroll
    for (int c = 0; c < 4; ++c) q += sse[c];
    q *= 1.25 / ((double)N_ROWS * (double)DIM);
    out[QOFF + 0] = (float)q;
    out[QOFF + 1] = (float)(red[0] / 1024.0);
    out[QOFF + 2] = (float)(pdscale * pdacc[0] / (double)NPAIRS);
  }
}

extern "C" void kernel_launch(void* const* d_in, const int* in_sizes, int n_in,
                              void* d_out, int out_size, void* d_ws, size_t ws_size,
                              hipStream_t stream) {
  const float* x  = (const float*)d_in[0];
  const float* cb = (const float*)d_in[1];
  float* out = (float*)d_out;

  char* w = (char*)d_ws;
  double* wn64   = (double*)(w);
  float*  sqw    = (float*) (w + 32768);
  int*    counts = (int*)   (w + 49152);
  double* sse    = (double*)(w + 65536);
  double* pdacc  = (double*)(w + 65568);
  _Float16* bws  = (_Float16*)(w + WS_BWS_OFF);

  zero_ws<<<16, 256, 0, stream>>>(counts, sse, pdacc);
  np_sqw_kernel<<<16, 256, 0, stream>>>(cb, sqw);
  if (ws_size >= WS_NEEDED) {
    cvt_b_kernel<<<512, 256, 0, stream>>>(cb, bws);
    pdist_mfma<<<256, 256, 0, stream>>>(bws, sqw, pdacc);
    rvq_main_mfma<<<N_ROWS / RPB, 256, 0, stream>>>(x, cb, bws, sqw, counts, sse, out);
    finalize_kernel<<<1, 1024, 0, stream>>>(counts, sse, pdacc, out, 1.0);
  } else {
    wnorm_kernel<<<1024, 256, 0, stream>>>(cb, wn64);
    pdist_kernel<<<4096, 128, 0, stream>>>(cb, wn64, pdacc);
    rvq_main_fb<<<N_ROWS / RPB, 128, 0, stream>>>(x, cb, sqw, counts, sse, out);
    finalize_kernel<<<1, 1024, 0, stream>>>(counts, sse, pdacc, out, 2.0);
  }
}

// Round 4
// 1075.438 us; speedup vs baseline: 1.0216x; 1.0216x over previous
//
#include <hip/hip_runtime.h>
#include <math.h>
#include <float.h>

// ResidualVectorQuantizer — Round 7: Af-less occupancy + qacc regs, NO nt on reused data.
//
// np ref model (verified exact, absmax 0 in R2/R3/R5b/R6):
//   G = r @ W.T (sequential-k fmaf), dist = fl(fl(sq_r+sq_w) - fl(2G)),
//   idx = lex-(dist,k) argmin; sq_r/sq_w = numpy pairwise sum (128+128, 8 acc).
// Stage 1 ranks with fp16 MFMA; |np_dist - approx| <= MARGIN; the within-margin
// candidate set is collected exactly and rescored with the exact np formula.
//
// R7 (post-mortem driven):
//  * R6 regression root-caused to nt hints on REUSED data (q round-trip, x):
//    nt q-stores forced HBM write-through (+420 MB) and nt loads bypassed L2,
//    putting HBM latency in ph6. ALL loads now plain; nt only on the single
//    final c==3 q store (never re-read).
//  * qacc[4][8] register carry restored (R5b PASSED bit-exact; its +31us was
//    the nt-x confound, VGPR showed no spill): out written once, never read.
//  * Af-less Ar rebuild from resS f32 kept (4 blocks/CU, occupancy 44%).

#define N_ROWS 65536
#define DIM    256
#define K_NUM  1024
#define N_CB   4
#define RPB    32
#define QOFF   16777216     // N_ROWS*DIM
#define IDXOFF 16777219     // QOFF + 3 scalars
#define NPAIRS 523776
#define MARGIN 2.4e-4f

#define SWZV(row, dunit) ((row) * DIM + ((((dunit) ^ ((row) & 7))) << 1))
#define SWZ2(row, d)     ((row) * DIM + ((((((d) >> 1) ^ ((row) & 7))) << 1) | ((d) & 1)))

typedef _Float16 f16x8 __attribute__((ext_vector_type(8)));
typedef float    f32x4 __attribute__((ext_vector_type(4)));

// ---------------- ws layout ----------------
// [0, 32768)        double wn64[4096]      (fallback pdist only)
// [32768, 49152)    float  sqw[4096]       (np-exact ||w||^2)
// [49152, 65536)    int    counts[4096]
// [65536, 65568)    double sse[4]
// [65568, 65576)    double pdacc[1]
// [69632, 2166784)  _Float16 bws[1048576]  (fp16 codebooks, fragment-major)
#define WS_BWS_OFF 69632
#define WS_NEEDED  2166784

__device__ __forceinline__ bool lexless(float a, int ka, float b, int kb) {
  return (a < b) || (a == b && ka < kb);
}

__global__ void zero_ws(int* counts, double* sse, double* pdacc) {
  int t = blockIdx.x * blockDim.x + threadIdx.x;
  if (t < 4096) counts[t] = 0;
  if (t < 4) sse[t] = 0.0;
  if (t == 0) pdacc[0] = 0.0;
}

// np-exact sum(W*W, axis=1): pairwise structure for n=256
__global__ void np_sqw_kernel(const float* __restrict__ cb,
                              float* __restrict__ sqw) {
#pragma clang fp contract(off)
  int g = blockIdx.x * blockDim.x + threadIdx.x;  // 0..4095
  const float* row = cb + (size_t)g * DIM;
  float blk[2];
#pragma unroll
  for (int b = 0; b < 2; ++b) {
    const float* a = row + b * 128;
    float r[8];
#pragma unroll
    for (int j = 0; j < 8; ++j) { float v = a[j]; r[j] = v * v; }
    for (int i = 8; i < 128; i += 8) {
#pragma unroll
      for (int j = 0; j < 8; ++j) { float v = a[i + j]; r[j] = r[j] + v * v; }
    }
    blk[b] = ((r[0] + r[1]) + (r[2] + r[3])) + ((r[4] + r[5]) + (r[6] + r[7]));
  }
  sqw[g] = blk[0] + blk[1];
}

// codebooks -> fp16 fragment-major (global layout is linear, lane*8)
__global__ void cvt_b_kernel(const float* __restrict__ cb,
                             _Float16* __restrict__ bws) {
  int tg = blockIdx.x * blockDim.x + threadIdx.x;  // 131072 threads
  int row = tg >> 5;        // 0..4095
  int chunk = tg & 31;
  int c = row >> 10, n = row & 1023;
  int nt = n >> 4, nin = n & 15;
  int kk = chunk >> 2, quad = chunk & 3;
  const float* src = cb + (size_t)row * DIM + chunk * 8;
  f16x8 h;
#pragma unroll
  for (int j = 0; j < 8; ++j) h[j] = (_Float16)src[j];
  size_t dst = ((size_t)((c * 64 + nt) * 8 + kk) * 64 + quad * 16 + nin) * 8;
  *(f16x8*)(bws + dst) = h;
}

// all-pairs mean distance via fp16 MFMA Gram (precision irrelevant: thr 20.48)
__global__ __launch_bounds__(256) void pdist_mfma(
    const _Float16* __restrict__ bws, const float* __restrict__ sqw,
    double* __restrict__ pdacc) {
  int t = threadIdx.x, lane = t & 63, wq = t >> 6;
  int quad = lane >> 4, col = lane & 15;
  int c = blockIdx.x >> 6, iT = blockIdx.x & 63;
  const float* sq = sqw + c * K_NUM;
  const _Float16* base = bws + ((size_t)(c * 64) * 8) * 512 + lane * 8;
  f16x8 Ar[8];
#pragma unroll
  for (int kk = 0; kk < 8; ++kk)
    Ar[kk] = *(const f16x8*)(base + (size_t)(iT * 8 + kk) * 512);
  float bi[4];
#pragma unroll
  for (int r = 0; r < 4; ++r) bi[r] = sq[iT * 16 + quad * 4 + r];
  float sum = 0.f;
#pragma unroll 1
  for (int jt0 = 0; jt0 < 16; ++jt0) {
    int jt = wq * 16 + jt0;
    f16x8 Br[8];
#pragma unroll
    for (int kk = 0; kk < 8; ++kk)
      Br[kk] = *(const f16x8*)(base + (size_t)(jt * 8 + kk) * 512);
    f32x4 acc = {0.f, 0.f, 0.f, 0.f};
#pragma unroll
    for (int kk = 0; kk < 8; ++kk)
      acc = __builtin_amdgcn_mfma_f32_16x16x32_f16(Ar[kk], Br[kk], acc, 0, 0, 0);
    int j = jt * 16 + col;
    float bj = sq[j];
#pragma unroll
    for (int r = 0; r < 4; ++r) {
      int i = iT * 16 + quad * 4 + r;
      float d2 = bi[r] + bj - 2.0f * acc[r];
      if (i != j) sum += sqrtf(fmaxf(d2, 0.f));
    }
  }
  double ds = (double)sum;
#pragma unroll
  for (int off = 32; off; off >>= 1) ds += __shfl_xor(ds, off, 64);
  if (lane == 0) atomicAdd(pdacc, ds);
}

// ================= MFMA main kernel =================
__global__ __launch_bounds__(256, 4) void rvq_main_mfma(
    const float* __restrict__ x, const float* __restrict__ cb,
    const _Float16* __restrict__ bws, const float* __restrict__ sqw,
    int* __restrict__ counts, double* __restrict__ sse,
    float* __restrict__ out) {
  __shared__ float resS[RPB * DIM];                      // 32 KB, swizzled f32
  __shared__ float wminS[RPB * 4];
  __shared__ int hardCnt[RPB];
  __shared__ int hardIdx[RPB * 6];
  __shared__ int idxS[RPB];
  __shared__ float sqrS[RPB];

  int t = threadIdx.x;            // 0..255
  int lane = t & 63, wq = t >> 6;
  int quad = lane >> 4, m16 = lane & 15;
  int rb = blockIdx.x * RPB;
  int dchunk = t & 31, rowgrp = t >> 5;   // update/staging mapping (8d chunks)

  // quantized accumulator, per-thread ownership = 4 rows x 8 dims (bit-exact,
  // verified R5b); out is written ONCE at c==3 and never read.
  float qacc[4][8];

  // ---- stage: residual = x -> resS (f32); PLAIN load (x re-read at c=1,2) --
#pragma unroll
  for (int i = 0; i < 4; ++i) {
    int row = rowgrp * 4 + i;
    size_t go = (size_t)(rb + row) * DIM + dchunk * 8;
    float xv[8];
    *(float4*)&xv[0] = *(const float4*)&x[go];
    *(float4*)&xv[4] = *(const float4*)&x[go + 4];
    int u0 = dchunk * 4;
    *(float2*)&resS[SWZV(row, u0 + 0)] = make_float2(xv[0], xv[1]);
    *(float2*)&resS[SWZV(row, u0 + 1)] = make_float2(xv[2], xv[3]);
    *(float2*)&resS[SWZV(row, u0 + 2)] = make_float2(xv[4], xv[5]);
    *(float2*)&resS[SWZV(row, u0 + 3)] = make_float2(xv[6], xv[7]);
  }
  __syncthreads();

  for (int c = 0; c < N_CB; ++c) {
    const float* cbl = cb + (size_t)c * K_NUM * DIM;
    const float* sqwl = sqw + c * K_NUM;

    // ---- ph0: np-exact sq_r per row (8-lane pairwise replica) ----
    {
#pragma clang fp contract(off)
      int kg = t & 7, rg = t >> 3;
      float blk[2];
#pragma unroll
      for (int b = 0; b < 2; ++b) {
        float v0 = resS[SWZ2(rg, b * 128 + kg)];
        float acc = v0 * v0;
        for (int i = 1; i < 16; ++i) {
          float v = resS[SWZ2(rg, b * 128 + kg + 8 * i)];
          acc = acc + v * v;
        }
        acc = acc + __shfl_xor(acc, 1, 8);
        acc = acc + __shfl_xor(acc, 2, 8);
        acc = acc + __shfl_xor(acc, 4, 8);
        blk[b] = acc;
      }
      if (kg == 0) sqrS[rg] = blk[0] + blk[1];
    }

    // ---- ph2: MFMA scoring; A-frags rebuilt from resS f32 (bit-identical
    //      single f32->f16 rounding), B streamed from L2 ----
    f16x8 Ar[2][8];
#pragma unroll
    for (int mt = 0; mt < 2; ++mt) {
      int arow = mt * 16 + m16;
#pragma unroll
      for (int kk = 0; kk < 8; ++kk) {
        f16x8 h;
#pragma unroll
        for (int jj = 0; jj < 4; ++jj) {
          float2 p = *(const float2*)&resS[SWZV(arow, kk * 16 + quad * 4 + jj)];
          h[2 * jj]     = (_Float16)p.x;
          h[2 * jj + 1] = (_Float16)p.y;
        }
        Ar[mt][kk] = h;
      }
    }
    float s1[2][4], s2[2][4]; int k1[2][4], k2[2][4];
#pragma unroll
    for (int mt = 0; mt < 2; ++mt)
#pragma unroll
      for (int r = 0; r < 4; ++r) {
        s1[mt][r] = FLT_MAX; s2[mt][r] = FLT_MAX;
        k1[mt][r] = 0x7FFFFFFF; k2[mt][r] = 0x7FFFFFFF;
      }
    const _Float16* Bc = bws + (size_t)((c * 64 + wq * 16) * 8) * 512 + lane * 8;
#pragma unroll 1
    for (int nt = 0; nt < 16; ++nt) {
      const _Float16* Bp = Bc + (size_t)nt * 8 * 512;
      f16x8 Br[8];
#pragma unroll
      for (int kk = 0; kk < 8; ++kk)
        Br[kk] = *(const f16x8*)(Bp + (size_t)kk * 512);
      f32x4 acc0 = {0.f, 0.f, 0.f, 0.f}, acc1 = {0.f, 0.f, 0.f, 0.f};
#pragma unroll
      for (int kk = 0; kk < 8; ++kk) {
        acc0 = __builtin_amdgcn_mfma_f32_16x16x32_f16(Ar[0][kk], Br[kk], acc0, 0, 0, 0);
        acc1 = __builtin_amdgcn_mfma_f32_16x16x32_f16(Ar[1][kk], Br[kk], acc1, 0, 0, 0);
      }
      int n = (wq * 16 + nt) * 16 + m16;
      float w2 = sqwl[n];
#pragma unroll
      for (int r = 0; r < 4; ++r) {
        float sa = w2 - 2.0f * acc0[r];
        if (sa < s1[0][r]) { s2[0][r] = s1[0][r]; k2[0][r] = k1[0][r]; s1[0][r] = sa; k1[0][r] = n; }
        else if (sa < s2[0][r]) { s2[0][r] = sa; k2[0][r] = n; }
        float sb = w2 - 2.0f * acc1[r];
        if (sb < s1[1][r]) { s2[1][r] = s1[1][r]; k2[1][r] = k1[1][r]; s1[1][r] = sb; k1[1][r] = n; }
        else if (sb < s2[1][r]) { s2[1][r] = sb; k2[1][r] = n; }
      }
    }

    // ---- step1: per-wave row-min -> wminS; zero hardCnt ----
    if (t < RPB) hardCnt[t] = 0;
#pragma unroll
    for (int mt = 0; mt < 2; ++mt)
#pragma unroll
      for (int r = 0; r < 4; ++r) {
        float mn = s1[mt][r];
#pragma unroll
        for (int off = 1; off <= 8; off <<= 1)
          mn = fminf(mn, __shfl_xor(mn, off, 16));
        if (m16 == 0) wminS[(mt * 16 + quad * 4 + r) * 4 + wq] = mn;
      }
    __syncthreads();

    // ---- step2: global thr; collect within-margin candidates via LDS atomics
#pragma unroll
    for (int mt = 0; mt < 2; ++mt)
#pragma unroll
      for (int r = 0; r < 4; ++r) {
        int row = mt * 16 + quad * 4 + r;
        float thr = fminf(fminf(wminS[row * 4 + 0], wminS[row * 4 + 1]),
                          fminf(wminS[row * 4 + 2], wminS[row * 4 + 3])) + MARGIN;
        bool c1 = s1[mt][r] <= thr;
        if (c1) {
          bool c2 = s2[mt][r] <= thr;
          int pos = atomicAdd(&hardCnt[row], 1 + (c2 ? 1 : 0));
          if (pos < 6) hardIdx[row * 6 + pos] = k1[mt][r];
          if (c2 && pos + 1 < 6) hardIdx[row * 6 + pos + 1] = k2[mt][r];
        }
      }
    __syncthreads();

    // ---- ph5: winner per row (cnt==1 fast; else exact np rescore) ----
    {
      int kg = t & 7, rg = t >> 3;
      int cnt = hardCnt[rg]; if (cnt > 6) cnt = 6;
      int winner;
      if (cnt == 1) {
        winner = hardIdx[rg * 6];
      } else {
        float myd = FLT_MAX; int myk = 0x7FFFFFFF;
        if (kg < cnt) {
          int k = hardIdx[rg * 6 + kg];
          const float* wrow = cbl + (size_t)k * DIM;
          float gsum = 0.0f;
#pragma unroll 8
          for (int d = 0; d < DIM; ++d)
            gsum = __builtin_fmaf(wrow[d], resS[SWZ2(rg, d)], gsum);
          float T = sqrS[rg] + sqwl[k];   // fl(sq_r + sq_w)
          myd = T - 2.0f * gsum;          // fl(T - 2g), 2g exact
          myk = k;
        }
#pragma unroll
        for (int off = 1; off <= 4; off <<= 1) {
          float od = __shfl_xor(myd, off, 8);
          int   ok = __shfl_xor(myk, off, 8);
          if (lexless(od, ok, myd, myk)) { myd = od; myk = ok; }
        }
        winner = myk;
      }
      if (kg == 0) {
        idxS[rg] = winner;
        out[(size_t)IDXOFF + (size_t)c * N_ROWS + rb + rg] = (float)winner;
        atomicAdd(&counts[c * K_NUM + winner], 1);
      }
    }
    __syncthreads();

    // ---- ph6: exact f32 update chain (rv from resS, qacc in regs) ----
    // per-elem chain (verified exact): rv == fl(x - q_prev) (stored resS)
    //   e = wv - rv; qs = rv + e; qn = q_prev + qs; rn = fl(x - qn)
    double lsse = 0.0;
#pragma unroll
    for (int i = 0; i < 4; ++i) {
      int row = rowgrp * 4 + i;
      int widx = idxS[row];
      size_t go = (size_t)(rb + row) * DIM + dchunk * 8;
      float wv[8], rv[8], xv[8];
      const float* wrow = cbl + (size_t)widx * DIM + dchunk * 8;
      *(float4*)&wv[0] = *(const float4*)&wrow[0];
      *(float4*)&wv[4] = *(const float4*)&wrow[4];
      int u0 = dchunk * 4;
      *(float2*)&rv[0] = *(const float2*)&resS[SWZV(row, u0 + 0)];
      *(float2*)&rv[2] = *(const float2*)&resS[SWZV(row, u0 + 1)];
      *(float2*)&rv[4] = *(const float2*)&resS[SWZV(row, u0 + 2)];
      *(float2*)&rv[6] = *(const float2*)&resS[SWZV(row, u0 + 3)];
      if (c == 1 || c == 2) {   // levels needing rn = fl(x - qn); PLAIN load
        *(float4*)&xv[0] = *(const float4*)&x[go];
        *(float4*)&xv[4] = *(const float4*)&x[go + 4];
      }
      float rnv[8];
#pragma unroll
      for (int j = 0; j < 8; ++j) {
        float e = wv[j] - rv[j];                       // e = q - r
        float qs = rv[j] + e;                          // q_st
        float qn = (c == 0) ? qs : (qacc[i][j] + qs);  // quantized accum
        qacc[i][j] = qn;
        lsse += (double)e * (double)e;
        if (c < N_CB - 1) {
          // c==0: x == rv (resS held x), bit-exact; c==1,2: x from global
          rnv[j] = (c == 0) ? (rv[j] - qn) : (xv[j] - qn);
        }
      }
      if (c < N_CB - 1) {
        *(float2*)&resS[SWZV(row, u0 + 0)] = make_float2(rnv[0], rnv[1]);
        *(float2*)&resS[SWZV(row, u0 + 1)] = make_float2(rnv[2], rnv[3]);
        *(float2*)&resS[SWZV(row, u0 + 2)] = make_float2(rnv[4], rnv[5]);
        *(float2*)&resS[SWZV(row, u0 + 3)] = make_float2(rnv[6], rnv[7]);
      } else {
        // final level: write quantized once, never re-read -> nt store
        f32x4 o0, o1;
#pragma unroll
        for (int j = 0; j < 4; ++j) { o0[j] = qacc[i][j]; o1[j] = qacc[i][4 + j]; }
        __builtin_nontemporal_store(o0, (f32x4*)&out[go]);
        __builtin_nontemporal_store(o1, (f32x4*)&out[go + 4]);
      }
    }
#pragma unroll
    for (int off = 32; off; off >>= 1) lsse += __shfl_xor(lsse, off, 64);
    if ((t & 63) == 0) atomicAdd(&sse[c], lsse);
    __syncthreads();
  }  // levels
}

// ================= fallback path (small ws): R2 VALU kernels ================
__global__ void wnorm_kernel(const float* __restrict__ cb,
                             double* __restrict__ wn64) {
  int gw = blockIdx.x * 4 + (threadIdx.x >> 6);
  int lane = threadIdx.x & 63;
  const float* row = cb + (size_t)gw * DIM;
  float4 v = *(const float4*)(row + lane * 4);
  double s = (double)v.x * v.x + (double)v.y * v.y +
             (double)v.z * v.z + (double)v.w * v.w;
#pragma unroll
  for (int off = 32; off; off >>= 1) s += __shfl_xor(s, off, 64);
  if (lane == 0) wn64[gw] = s;
}

__global__ void pdist_kernel(const float* __restrict__ cb,
                             const double* __restrict__ wn64,
                             double* __restrict__ pdacc) {
  __shared__ float wi[DIM];
  int c = blockIdx.x >> 10;
  int i = blockIdx.x & 1023;
  int t = threadIdx.x;  // 128
  const float* rowi = cb + ((size_t)c * K_NUM + i) * DIM;
  *(float2*)&wi[t * 2] = *(const float2*)&rowi[t * 2];
  __syncthreads();
  double bi = wn64[c * K_NUM + i];
  double lsum = 0.0;
  for (int j = i + 1 + t; j < K_NUM; j += 128) {
    const float* rowj = cb + ((size_t)c * K_NUM + j) * DIM;
    double dot = 0.0;
#pragma unroll 8
    for (int d = 0; d < DIM; ++d) dot += (double)rowj[d] * (double)wi[d];
    double d2 = bi + wn64[c * K_NUM + j] - 2.0 * dot;
    lsum += sqrt(fmax(d2, 0.0));
  }
#pragma unroll
  for (int off = 32; off; off >>= 1) lsum += __shfl_xor(lsum, off, 64);
  if ((t & 63) == 0) atomicAdd(pdacc, lsum);
}

__global__ __launch_bounds__(128) void rvq_main_fb(
    const float* __restrict__ x, const float* __restrict__ cb,
    const float* __restrict__ sqw,
    int* __restrict__ counts, double* __restrict__ sse,
    float* __restrict__ out) {
  __shared__ float Wt[RPB * DIM];
  __shared__ float resS[RPB * DIM];
  int t = threadIdx.x;
  int kg = t & 7;
  int rg = t >> 3;
  int rb = blockIdx.x * RPB;
#pragma unroll 4
  for (int it = 0; it < RPB; ++it) {
    float2 v = *(const float2*)&x[(size_t)(rb + it) * DIM + t * 2];
    *(float2*)&resS[SWZV(it, t)] = v;
  }
  __syncthreads();
  for (int c = 0; c < N_CB; ++c) {
    const float* cbl = cb + (size_t)c * K_NUM * DIM;
    const float* sqwl = sqw + c * K_NUM;
    float sqr[2];
    {
#pragma clang fp contract(off)
#pragma unroll
      for (int j = 0; j < 2; ++j) {
        int row = rg + 16 * j;
        float blk[2];
#pragma unroll
        for (int b = 0; b < 2; ++b) {
          float v0 = resS[SWZ2(row, b * 128 + kg)];
          float acc = v0 * v0;
          for (int i = 1; i < 16; ++i) {
            float v = resS[SWZ2(row, b * 128 + kg + 8 * i)];
            acc = acc + v * v;
          }
          acc = acc + __shfl_xor(acc, 1, 8);
          acc = acc + __shfl_xor(acc, 2, 8);
          acc = acc + __shfl_xor(acc, 4, 8);
          blk[b] = acc;
        }
        sqr[j] = blk[0] + blk[1];
      }
    }
    float m1[2], m2[2]; int i1[2], i2[2];
    m1[0] = m1[1] = m2[0] = m2[1] = FLT_MAX;
    i1[0] = i1[1] = i2[0] = i2[1] = 0x7FFFFFFF;
    for (int tile = 0; tile < K_NUM / 32; ++tile) {
      __syncthreads();
      const float* wsrc = cbl + (size_t)tile * 32 * DIM;
#pragma unroll 4
      for (int it = 0; it < 32; ++it) {
        float2 v = *(const float2*)&wsrc[(size_t)it * DIM + t * 2];
        *(float2*)&Wt[SWZV(it, t)] = v;
      }
      __syncthreads();
      float acc[4][2] = {{0.f, 0.f}, {0.f, 0.f}, {0.f, 0.f}, {0.f, 0.f}};
#pragma unroll 8
      for (int du = 0; du < DIM / 2; ++du) {
        float2 r0 = *(const float2*)&resS[SWZV(rg, du)];
        float2 r1 = *(const float2*)&resS[SWZV(rg + 16, du)];
#pragma unroll
        for (int i = 0; i < 4; ++i) {
          int k = kg + 8 * i;
          float2 w = *(const float2*)&Wt[SWZV(k, du)];
          acc[i][0] += w.x * r0.x; acc[i][0] += w.y * r0.y;
          acc[i][1] += w.x * r1.x; acc[i][1] += w.y * r1.y;
        }
      }
#pragma unroll
      for (int i = 0; i < 4; ++i) {
        int k = tile * 32 + kg + 8 * i;
        float b = sqwl[k];
#pragma unroll
        for (int j = 0; j < 2; ++j) {
          float s = b - 2.0f * acc[i][j];
          if (lexless(s, k, m1[j], i1[j])) {
            m2[j] = m1[j]; i2[j] = i1[j]; m1[j] = s; i1[j] = k;
          } else if (lexless(s, k, m2[j], i2[j])) {
            m2[j] = s; i2[j] = k;
          }
        }
      }
    }
    float as[2][4]; int ak[2][4];
#pragma unroll
    for (int j = 0; j < 2; ++j) {
      as[j][0] = m1[j]; ak[j][0] = i1[j];
      as[j][1] = m2[j]; ak[j][1] = i2[j];
      as[j][2] = FLT_MAX; ak[j][2] = 0x7FFFFFFF;
      as[j][3] = FLT_MAX; ak[j][3] = 0x7FFFFFFF;
#pragma unroll
      for (int off = 1; off <= 4; off <<= 1) {
        float bs[4]; int bk[4];
#pragma unroll
        for (int q = 0; q < 4; ++q) {
          bs[q] = __shfl_xor(as[j][q], off, 8);
          bk[q] = __shfl_xor(ak[j][q], off, 8);
        }
        float cs[4]; int ck[4];
#pragma unroll
        for (int q = 0; q < 4; ++q) {
          bool ta = lexless(as[j][q], ak[j][q], bs[3 - q], bk[3 - q]);
          cs[q] = ta ? as[j][q] : bs[3 - q];
          ck[q] = ta ? ak[j][q] : bk[3 - q];
        }
#define CE(p, q) { bool sw = lexless(cs[q], ck[q], cs[p], ck[p]); \
                   float ts = sw ? cs[q] : cs[p]; int tk = sw ? ck[q] : ck[p]; \
                   cs[q] = sw ? cs[p] : cs[q]; ck[q] = sw ? ck[p] : ck[q]; \
                   cs[p] = ts; ck[p] = tk; }
        CE(0, 2) CE(1, 3) CE(0, 1) CE(2, 3)
#undef CE
#pragma unroll
        for (int q = 0; q < 4; ++q) { as[j][q] = cs[q]; ak[j][q] = ck[q]; }
      }
    }
    int winner[2];
#pragma unroll
    for (int j = 0; j < 2; ++j) {
      if (as[j][1] <= as[j][0] + 1.2e-4f) {
        int row = rg + 16 * j;
        float ss = (kg == 0) ? as[j][0] : (kg == 1) ? as[j][1]
                 : (kg == 2) ? as[j][2] : (kg == 3) ? as[j][3] : FLT_MAX;
        int   sk = (kg == 0) ? ak[j][0] : (kg == 1) ? ak[j][1]
                 : (kg == 2) ? ak[j][2] : (kg == 3) ? ak[j][3] : 0x7FFFFFFF;
        float myd = FLT_MAX; int myk = 0x7FFFFFFF;
        if (kg < 4 && ss <= as[j][0] + 1.2e-4f) {
          const float* wrow = cbl + (size_t)sk * DIM;
          float g = 0.0f;
#pragma unroll 8
          for (int d = 0; d < DIM; ++d)
            g = __builtin_fmaf(wrow[d], resS[SWZ2(row, d)], g);
          float T = sqr[j] + sqwl[sk];
          myd = T - 2.0f * g;
          myk = sk;
        }
#pragma unroll
        for (int off = 1; off <= 4; off <<= 1) {
          float od = __shfl_xor(myd, off, 8);
          int   ok = __shfl_xor(myk, off, 8);
          if (lexless(od, ok, myd, myk)) { myd = od; myk = ok; }
        }
        winner[j] = myk;
      } else {
        winner[j] = ak[j][0];
      }
    }
    __syncthreads();
    int* idxSf = (int*)Wt;
    if (kg == 0) {
      idxSf[rg] = winner[0];
      idxSf[rg + 16] = winner[1];
      out[(size_t)IDXOFF + (size_t)c * N_ROWS + rb + rg] = (float)winner[0];
      out[(size_t)IDXOFF + (size_t)c * N_ROWS + rb + rg + 16] = (float)winner[1];
      atomicAdd(&counts[c * K_NUM + winner[0]], 1);
      atomicAdd(&counts[c * K_NUM + winner[1]], 1);
    }
    __syncthreads();
    double lsse = 0.0;
#pragma unroll 4
    for (int it = 0; it < RPB; ++it) {
      int widx = idxSf[it];
      size_t go = (size_t)(rb + it) * DIM + t * 2;
      float2 wv = *(const float2*)&cbl[(size_t)widx * DIM + t * 2];
      float2 rv = *(const float2*)&resS[SWZV(it, t)];
      float ex = wv.x - rv.x, ey = wv.y - rv.y;
      float qsx = rv.x + ex, qsy = rv.y + ey;
      float qnx, qny;
      if (c == 0) { qnx = qsx; qny = qsy; }
      else { float2 qo = *(const float2*)&out[go]; qnx = qo.x + qsx; qny = qo.y + qsy; }
      *(float2*)&out[go] = make_float2(qnx, qny);
      float2 xv = *(const float2*)&x[go];
      float rnx = xv.x - qnx, rny = xv.y - qny;
      *(float2*)&resS[SWZV(it, t)] = make_float2(rnx, rny);
      lsse += (double)ex * (double)ex + (double)ey * (double)ey;
    }
#pragma unroll
    for (int off = 32; off; off >>= 1) lsse += __shfl_xor(lsse, off, 64);
    if ((t & 63) == 0) atomicAdd(&sse[c], lsse);
    __syncthreads();
  }
}

__global__ void finalize_kernel(const int* __restrict__ counts,
                                const double* __restrict__ sse,
                                const double* __restrict__ pdacc,
                                float* __restrict__ out, double pdscale) {
  __shared__ double red[1024];
  int t = threadIdx.x;
  double u = 0.0;
#pragma unroll
  for (int c = 0; c < 4; ++c) u += fabs((double)counts[c * 1024 + t] - 64.0);
  red[t] = u;
  __syncthreads();
  for (int s = 512; s; s >>= 1) {
    if (t < s) red[t] += red[t + s];
    __syncthreads();
  }
  if (t == 0) {
    double q = 0.0;
#pragma unroll
    for (int c = 0; c < 4; ++c) q += sse[c];
    q *= 1.25 / ((double)N_ROWS * (double)DIM);
    out[QOFF + 0] = (float)q;
    out[QOFF + 1] = (float)(red[0] / 1024.0);
    out[QOFF + 2] = (float)(pdscale * pdacc[0] / (double)NPAIRS);
  }
}

extern "C" void kernel_launch(void* const* d_in, const int* in_sizes, int n_in,
                              void* d_out, int out_size, void* d_ws, size_t ws_size,
                              hipStream_t stream) {
  const float* x  = (const float*)d_in[0];
  const float* cb = (const float*)d_in[1];
  float* out = (float*)d_out;

  char* w = (char*)d_ws;
  double* wn64   = (double*)(w);
  float*  sqw    = (float*) (w + 32768);
  int*    counts = (int*)   (w + 49152);
  double* sse    = (double*)(w + 65536);
  double* pdacc  = (double*)(w + 65568);
  _Float16* bws  = (_Float16*)(w + WS_BWS_OFF);

  zero_ws<<<16, 256, 0, stream>>>(counts, sse, pdacc);
  np_sqw_kernel<<<16, 256, 0, stream>>>(cb, sqw);
  if (ws_size >= WS_NEEDED) {
    cvt_b_kernel<<<512, 256, 0, stream>>>(cb, bws);
    pdist_mfma<<<256, 256, 0, stream>>>(bws, sqw, pdacc);
    rvq_main_mfma<<<N_ROWS / RPB, 256, 0, stream>>>(x, cb, bws, sqw, counts, sse, out);
    finalize_kernel<<<1, 1024, 0, stream>>>(counts, sse, pdacc, out, 1.0);
  } else {
    wnorm_kernel<<<1024, 256, 0, stream>>>(cb, wn64);
    pdist_kernel<<<4096, 128, 0, stream>>>(cb, wn64, pdacc);
    rvq_main_fb<<<N_ROWS / RPB, 128, 0, stream>>>(x, cb, sqw, counts, sse, out);
    finalize_kernel<<<1, 1024, 0, stream>>>(counts, sse, pdacc, out, 2.0);
  }
}

// Round 5
// 1075.052 us; speedup vs baseline: 1.0220x; 1.0004x over previous
//
#include <hip/hip_runtime.h>
#include <math.h>
#include <float.h>

// ResidualVectorQuantizer — Round 8: lift VGPR cap (spill-traffic theory test).
//
// np ref model (verified exact, absmax 0 in R2/R3/R5b/R6/R7):
//   G = r @ W.T (sequential-k fmaf), dist = fl(fl(sq_r+sq_w) - fl(2G)),
//   idx = lex-(dist,k) argmin; sq_r/sq_w = numpy pairwise sum (128+128, 8 acc).
// Stage 1 ranks with fp16 MFMA; |np_dist - approx| <= MARGIN; the within-margin
// candidate set is collected exactly and rescored with the exact np formula.
//
// R8 (single change vs R7): __launch_bounds__(256,4) -> (256,2).
//   R7 post-mortem: removing 384 MB structural traffic changed FETCH/WRITE by
//   ZERO; excess is ~750 MB symmetric R+W = scratch spill (Ar[2][8]=64 VGPRs
//   alone vs VGPR_Count=64 forced by the old bound). Cap 256 lets the natural
//   ~150-reg working set live in registers; expect spill traffic to vanish.

#define N_ROWS 65536
#define DIM    256
#define K_NUM  1024
#define N_CB   4
#define RPB    32
#define QOFF   16777216     // N_ROWS*DIM
#define IDXOFF 16777219     // QOFF + 3 scalars
#define NPAIRS 523776
#define MARGIN 2.4e-4f

#define SWZV(row, dunit) ((row) * DIM + ((((dunit) ^ ((row) & 7))) << 1))
#define SWZ2(row, d)     ((row) * DIM + ((((((d) >> 1) ^ ((row) & 7))) << 1) | ((d) & 1)))

typedef _Float16 f16x8 __attribute__((ext_vector_type(8)));
typedef float    f32x4 __attribute__((ext_vector_type(4)));

// ---------------- ws layout ----------------
// [0, 32768)        double wn64[4096]      (fallback pdist only)
// [32768, 49152)    float  sqw[4096]       (np-exact ||w||^2)
// [49152, 65536)    int    counts[4096]
// [65536, 65568)    double sse[4]
// [65568, 65576)    double pdacc[1]
// [69632, 2166784)  _Float16 bws[1048576]  (fp16 codebooks, fragment-major)
#define WS_BWS_OFF 69632
#define WS_NEEDED  2166784

__device__ __forceinline__ bool lexless(float a, int ka, float b, int kb) {
  return (a < b) || (a == b && ka < kb);
}

__global__ void zero_ws(int* counts, double* sse, double* pdacc) {
  int t = blockIdx.x * blockDim.x + threadIdx.x;
  if (t < 4096) counts[t] = 0;
  if (t < 4) sse[t] = 0.0;
  if (t == 0) pdacc[0] = 0.0;
}

// np-exact sum(W*W, axis=1): pairwise structure for n=256
__global__ void np_sqw_kernel(const float* __restrict__ cb,
                              float* __restrict__ sqw) {
#pragma clang fp contract(off)
  int g = blockIdx.x * blockDim.x + threadIdx.x;  // 0..4095
  const float* row = cb + (size_t)g * DIM;
  float blk[2];
#pragma unroll
  for (int b = 0; b < 2; ++b) {
    const float* a = row + b * 128;
    float r[8];
#pragma unroll
    for (int j = 0; j < 8; ++j) { float v = a[j]; r[j] = v * v; }
    for (int i = 8; i < 128; i += 8) {
#pragma unroll
      for (int j = 0; j < 8; ++j) { float v = a[i + j]; r[j] = r[j] + v * v; }
    }
    blk[b] = ((r[0] + r[1]) + (r[2] + r[3])) + ((r[4] + r[5]) + (r[6] + r[7]));
  }
  sqw[g] = blk[0] + blk[1];
}

// codebooks -> fp16 fragment-major (global layout is linear, lane*8)
__global__ void cvt_b_kernel(const float* __restrict__ cb,
                             _Float16* __restrict__ bws) {
  int tg = blockIdx.x * blockDim.x + threadIdx.x;  // 131072 threads
  int row = tg >> 5;        // 0..4095
  int chunk = tg & 31;
  int c = row >> 10, n = row & 1023;
  int nt = n >> 4, nin = n & 15;
  int kk = chunk >> 2, quad = chunk & 3;
  const float* src = cb + (size_t)row * DIM + chunk * 8;
  f16x8 h;
#pragma unroll
  for (int j = 0; j < 8; ++j) h[j] = (_Float16)src[j];
  size_t dst = ((size_t)((c * 64 + nt) * 8 + kk) * 64 + quad * 16 + nin) * 8;
  *(f16x8*)(bws + dst) = h;
}

// all-pairs mean distance via fp16 MFMA Gram (precision irrelevant: thr 20.48)
__global__ __launch_bounds__(256) void pdist_mfma(
    const _Float16* __restrict__ bws, const float* __restrict__ sqw,
    double* __restrict__ pdacc) {
  int t = threadIdx.x, lane = t & 63, wq = t >> 6;
  int quad = lane >> 4, col = lane & 15;
  int c = blockIdx.x >> 6, iT = blockIdx.x & 63;
  const float* sq = sqw + c * K_NUM;
  const _Float16* base = bws + ((size_t)(c * 64) * 8) * 512 + lane * 8;
  f16x8 Ar[8];
#pragma unroll
  for (int kk = 0; kk < 8; ++kk)
    Ar[kk] = *(const f16x8*)(base + (size_t)(iT * 8 + kk) * 512);
  float bi[4];
#pragma unroll
  for (int r = 0; r < 4; ++r) bi[r] = sq[iT * 16 + quad * 4 + r];
  float sum = 0.f;
#pragma unroll 1
  for (int jt0 = 0; jt0 < 16; ++jt0) {
    int jt = wq * 16 + jt0;
    f16x8 Br[8];
#pragma unroll
    for (int kk = 0; kk < 8; ++kk)
      Br[kk] = *(const f16x8*)(base + (size_t)(jt * 8 + kk) * 512);
    f32x4 acc = {0.f, 0.f, 0.f, 0.f};
#pragma unroll
    for (int kk = 0; kk < 8; ++kk)
      acc = __builtin_amdgcn_mfma_f32_16x16x32_f16(Ar[kk], Br[kk], acc, 0, 0, 0);
    int j = jt * 16 + col;
    float bj = sq[j];
#pragma unroll
    for (int r = 0; r < 4; ++r) {
      int i = iT * 16 + quad * 4 + r;
      float d2 = bi[r] + bj - 2.0f * acc[r];
      if (i != j) sum += sqrtf(fmaxf(d2, 0.f));
    }
  }
  double ds = (double)sum;
#pragma unroll
  for (int off = 32; off; off >>= 1) ds += __shfl_xor(ds, off, 64);
  if (lane == 0) atomicAdd(pdacc, ds);
}

// ================= MFMA main kernel =================
__global__ __launch_bounds__(256, 2) void rvq_main_mfma(
    const float* __restrict__ x, const float* __restrict__ cb,
    const _Float16* __restrict__ bws, const float* __restrict__ sqw,
    int* __restrict__ counts, double* __restrict__ sse,
    float* __restrict__ out) {
  __shared__ float resS[RPB * DIM];                      // 32 KB, swizzled f32
  __shared__ float wminS[RPB * 4];
  __shared__ int hardCnt[RPB];
  __shared__ int hardIdx[RPB * 6];
  __shared__ int idxS[RPB];
  __shared__ float sqrS[RPB];

  int t = threadIdx.x;            // 0..255
  int lane = t & 63, wq = t >> 6;
  int quad = lane >> 4, m16 = lane & 15;
  int rb = blockIdx.x * RPB;
  int dchunk = t & 31, rowgrp = t >> 5;   // update/staging mapping (8d chunks)

  // quantized accumulator, per-thread ownership = 4 rows x 8 dims (bit-exact,
  // verified R5b); out is written ONCE at c==3 and never read.
  float qacc[4][8];

  // ---- stage: residual = x -> resS (f32); PLAIN load (x re-read at c=1,2) --
#pragma unroll
  for (int i = 0; i < 4; ++i) {
    int row = rowgrp * 4 + i;
    size_t go = (size_t)(rb + row) * DIM + dchunk * 8;
    float xv[8];
    *(float4*)&xv[0] = *(const float4*)&x[go];
    *(float4*)&xv[4] = *(const float4*)&x[go + 4];
    int u0 = dchunk * 4;
    *(float2*)&resS[SWZV(row, u0 + 0)] = make_float2(xv[0], xv[1]);
    *(float2*)&resS[SWZV(row, u0 + 1)] = make_float2(xv[2], xv[3]);
    *(float2*)&resS[SWZV(row, u0 + 2)] = make_float2(xv[4], xv[5]);
    *(float2*)&resS[SWZV(row, u0 + 3)] = make_float2(xv[6], xv[7]);
  }
  __syncthreads();

  for (int c = 0; c < N_CB; ++c) {
    const float* cbl = cb + (size_t)c * K_NUM * DIM;
    const float* sqwl = sqw + c * K_NUM;

    // ---- ph0: np-exact sq_r per row (8-lane pairwise replica) ----
    {
#pragma clang fp contract(off)
      int kg = t & 7, rg = t >> 3;
      float blk[2];
#pragma unroll
      for (int b = 0; b < 2; ++b) {
        float v0 = resS[SWZ2(rg, b * 128 + kg)];
        float acc = v0 * v0;
        for (int i = 1; i < 16; ++i) {
          float v = resS[SWZ2(rg, b * 128 + kg + 8 * i)];
          acc = acc + v * v;
        }
        acc = acc + __shfl_xor(acc, 1, 8);
        acc = acc + __shfl_xor(acc, 2, 8);
        acc = acc + __shfl_xor(acc, 4, 8);
        blk[b] = acc;
      }
      if (kg == 0) sqrS[rg] = blk[0] + blk[1];
    }

    // ---- ph2: MFMA scoring; A-frags rebuilt from resS f32 (bit-identical
    //      single f32->f16 rounding), B streamed from L2 ----
    f16x8 Ar[2][8];
#pragma unroll
    for (int mt = 0; mt < 2; ++mt) {
      int arow = mt * 16 + m16;
#pragma unroll
      for (int kk = 0; kk < 8; ++kk) {
        f16x8 h;
#pragma unroll
        for (int jj = 0; jj < 4; ++jj) {
          float2 p = *(const float2*)&resS[SWZV(arow, kk * 16 + quad * 4 + jj)];
          h[2 * jj]     = (_Float16)p.x;
          h[2 * jj + 1] = (_Float16)p.y;
        }
        Ar[mt][kk] = h;
      }
    }
    float s1[2][4], s2[2][4]; int k1[2][4], k2[2][4];
#pragma unroll
    for (int mt = 0; mt < 2; ++mt)
#pragma unroll
      for (int r = 0; r < 4; ++r) {
        s1[mt][r] = FLT_MAX; s2[mt][r] = FLT_MAX;
        k1[mt][r] = 0x7FFFFFFF; k2[mt][r] = 0x7FFFFFFF;
      }
    const _Float16* Bc = bws + (size_t)((c * 64 + wq * 16) * 8) * 512 + lane * 8;
#pragma unroll 1
    for (int nt = 0; nt < 16; ++nt) {
      const _Float16* Bp = Bc + (size_t)nt * 8 * 512;
      f16x8 Br[8];
#pragma unroll
      for (int kk = 0; kk < 8; ++kk)
        Br[kk] = *(const f16x8*)(Bp + (size_t)kk * 512);
      f32x4 acc0 = {0.f, 0.f, 0.f, 0.f}, acc1 = {0.f, 0.f, 0.f, 0.f};
#pragma unroll
      for (int kk = 0; kk < 8; ++kk) {
        acc0 = __builtin_amdgcn_mfma_f32_16x16x32_f16(Ar[0][kk], Br[kk], acc0, 0, 0, 0);
        acc1 = __builtin_amdgcn_mfma_f32_16x16x32_f16(Ar[1][kk], Br[kk], acc1, 0, 0, 0);
      }
      int n = (wq * 16 + nt) * 16 + m16;
      float w2 = sqwl[n];
#pragma unroll
      for (int r = 0; r < 4; ++r) {
        float sa = w2 - 2.0f * acc0[r];
        if (sa < s1[0][r]) { s2[0][r] = s1[0][r]; k2[0][r] = k1[0][r]; s1[0][r] = sa; k1[0][r] = n; }
        else if (sa < s2[0][r]) { s2[0][r] = sa; k2[0][r] = n; }
        float sb = w2 - 2.0f * acc1[r];
        if (sb < s1[1][r]) { s2[1][r] = s1[1][r]; k2[1][r] = k1[1][r]; s1[1][r] = sb; k1[1][r] = n; }
        else if (sb < s2[1][r]) { s2[1][r] = sb; k2[1][r] = n; }
      }
    }

    // ---- step1: per-wave row-min -> wminS; zero hardCnt ----
    if (t < RPB) hardCnt[t] = 0;
#pragma unroll
    for (int mt = 0; mt < 2; ++mt)
#pragma unroll
      for (int r = 0; r < 4; ++r) {
        float mn = s1[mt][r];
#pragma unroll
        for (int off = 1; off <= 8; off <<= 1)
          mn = fminf(mn, __shfl_xor(mn, off, 16));
        if (m16 == 0) wminS[(mt * 16 + quad * 4 + r) * 4 + wq] = mn;
      }
    __syncthreads();

    // ---- step2: global thr; collect within-margin candidates via LDS atomics
#pragma unroll
    for (int mt = 0; mt < 2; ++mt)
#pragma unroll
      for (int r = 0; r < 4; ++r) {
        int row = mt * 16 + quad * 4 + r;
        float thr = fminf(fminf(wminS[row * 4 + 0], wminS[row * 4 + 1]),
                          fminf(wminS[row * 4 + 2], wminS[row * 4 + 3])) + MARGIN;
        bool c1 = s1[mt][r] <= thr;
        if (c1) {
          bool c2 = s2[mt][r] <= thr;
          int pos = atomicAdd(&hardCnt[row], 1 + (c2 ? 1 : 0));
          if (pos < 6) hardIdx[row * 6 + pos] = k1[mt][r];
          if (c2 && pos + 1 < 6) hardIdx[row * 6 + pos + 1] = k2[mt][r];
        }
      }
    __syncthreads();

    // ---- ph5: winner per row (cnt==1 fast; else exact np rescore) ----
    {
      int kg = t & 7, rg = t >> 3;
      int cnt = hardCnt[rg]; if (cnt > 6) cnt = 6;
      int winner;
      if (cnt == 1) {
        winner = hardIdx[rg * 6];
      } else {
        float myd = FLT_MAX; int myk = 0x7FFFFFFF;
        if (kg < cnt) {
          int k = hardIdx[rg * 6 + kg];
          const float* wrow = cbl + (size_t)k * DIM;
          float gsum = 0.0f;
#pragma unroll 8
          for (int d = 0; d < DIM; ++d)
            gsum = __builtin_fmaf(wrow[d], resS[SWZ2(rg, d)], gsum);
          float T = sqrS[rg] + sqwl[k];   // fl(sq_r + sq_w)
          myd = T - 2.0f * gsum;          // fl(T - 2g), 2g exact
          myk = k;
        }
#pragma unroll
        for (int off = 1; off <= 4; off <<= 1) {
          float od = __shfl_xor(myd, off, 8);
          int   ok = __shfl_xor(myk, off, 8);
          if (lexless(od, ok, myd, myk)) { myd = od; myk = ok; }
        }
        winner = myk;
      }
      if (kg == 0) {
        idxS[rg] = winner;
        out[(size_t)IDXOFF + (size_t)c * N_ROWS + rb + rg] = (float)winner;
        atomicAdd(&counts[c * K_NUM + winner], 1);
      }
    }
    __syncthreads();

    // ---- ph6: exact f32 update chain (rv from resS, qacc in regs) ----
    // per-elem chain (verified exact): rv == fl(x - q_prev) (stored resS)
    //   e = wv - rv; qs = rv + e; qn = q_prev + qs; rn = fl(x - qn)
    double lsse = 0.0;
#pragma unroll
    for (int i = 0; i < 4; ++i) {
      int row = rowgrp * 4 + i;
      int widx = idxS[row];
      size_t go = (size_t)(rb + row) * DIM + dchunk * 8;
      float wv[8], rv[8], xv[8];
      const float* wrow = cbl + (size_t)widx * DIM + dchunk * 8;
      *(float4*)&wv[0] = *(const float4*)&wrow[0];
      *(float4*)&wv[4] = *(const float4*)&wrow[4];
      int u0 = dchunk * 4;
      *(float2*)&rv[0] = *(const float2*)&resS[SWZV(row, u0 + 0)];
      *(float2*)&rv[2] = *(const float2*)&resS[SWZV(row, u0 + 1)];
      *(float2*)&rv[4] = *(const float2*)&resS[SWZV(row, u0 + 2)];
      *(float2*)&rv[6] = *(const float2*)&resS[SWZV(row, u0 + 3)];
      if (c == 1 || c == 2) {   // levels needing rn = fl(x - qn); PLAIN load
        *(float4*)&xv[0] = *(const float4*)&x[go];
        *(float4*)&xv[4] = *(const float4*)&x[go + 4];
      }
      float rnv[8];
#pragma unroll
      for (int j = 0; j < 8; ++j) {
        float e = wv[j] - rv[j];                       // e = q - r
        float qs = rv[j] + e;                          // q_st
        float qn = (c == 0) ? qs : (qacc[i][j] + qs);  // quantized accum
        qacc[i][j] = qn;
        lsse += (double)e * (double)e;
        if (c < N_CB - 1) {
          // c==0: x == rv (resS held x), bit-exact; c==1,2: x from global
          rnv[j] = (c == 0) ? (rv[j] - qn) : (xv[j] - qn);
        }
      }
      if (c < N_CB - 1) {
        *(float2*)&resS[SWZV(row, u0 + 0)] = make_float2(rnv[0], rnv[1]);
        *(float2*)&resS[SWZV(row, u0 + 1)] = make_float2(rnv[2], rnv[3]);
        *(float2*)&resS[SWZV(row, u0 + 2)] = make_float2(rnv[4], rnv[5]);
        *(float2*)&resS[SWZV(row, u0 + 3)] = make_float2(rnv[6], rnv[7]);
      } else {
        // final level: write quantized once, never re-read -> nt store
        f32x4 o0, o1;
#pragma unroll
        for (int j = 0; j < 4; ++j) { o0[j] = qacc[i][j]; o1[j] = qacc[i][4 + j]; }
        __builtin_nontemporal_store(o0, (f32x4*)&out[go]);
        __builtin_nontemporal_store(o1, (f32x4*)&out[go + 4]);
      }
    }
#pragma unroll
    for (int off = 32; off; off >>= 1) lsse += __shfl_xor(lsse, off, 64);
    if ((t & 63) == 0) atomicAdd(&sse[c], lsse);
    __syncthreads();
  }  // levels
}

// ================= fallback path (small ws): R2 VALU kernels ================
__global__ void wnorm_kernel(const float* __restrict__ cb,
                             double* __restrict__ wn64) {
  int gw = blockIdx.x * 4 + (threadIdx.x >> 6);
  int lane = threadIdx.x & 63;
  const float* row = cb + (size_t)gw * DIM;
  float4 v = *(const float4*)(row + lane * 4);
  double s = (double)v.x * v.x + (double)v.y * v.y +
             (double)v.z * v.z + (double)v.w * v.w;
#pragma unroll
  for (int off = 32; off; off >>= 1) s += __shfl_xor(s, off, 64);
  if (lane == 0) wn64[gw] = s;
}

__global__ void pdist_kernel(const float* __restrict__ cb,
                             const double* __restrict__ wn64,
                             double* __restrict__ pdacc) {
  __shared__ float wi[DIM];
  int c = blockIdx.x >> 10;
  int i = blockIdx.x & 1023;
  int t = threadIdx.x;  // 128
  const float* rowi = cb + ((size_t)c * K_NUM + i) * DIM;
  *(float2*)&wi[t * 2] = *(const float2*)&rowi[t * 2];
  __syncthreads();
  double bi = wn64[c * K_NUM + i];
  double lsum = 0.0;
  for (int j = i + 1 + t; j < K_NUM; j += 128) {
    const float* rowj = cb + ((size_t)c * K_NUM + j) * DIM;
    double dot = 0.0;
#pragma unroll 8
    for (int d = 0; d < DIM; ++d) dot += (double)rowj[d] * (double)wi[d];
    double d2 = bi + wn64[c * K_NUM + j] - 2.0 * dot;
    lsum += sqrt(fmax(d2, 0.0));
  }
#pragma unroll
  for (int off = 32; off; off >>= 1) lsum += __shfl_xor(lsum, off, 64);
  if ((t & 63) == 0) atomicAdd(pdacc, lsum);
}

__global__ __launch_bounds__(128) void rvq_main_fb(
    const float* __restrict__ x, const float* __restrict__ cb,
    const float* __restrict__ sqw,
    int* __restrict__ counts, double* __restrict__ sse,
    float* __restrict__ out) {
  __shared__ float Wt[RPB * DIM];
  __shared__ float resS[RPB * DIM];
  int t = threadIdx.x;
  int kg = t & 7;
  int rg = t >> 3;
  int rb = blockIdx.x * RPB;
#pragma unroll 4
  for (int it = 0; it < RPB; ++it) {
    float2 v = *(const float2*)&x[(size_t)(rb + it) * DIM + t * 2];
    *(float2*)&resS[SWZV(it, t)] = v;
  }
  __syncthreads();
  for (int c = 0; c < N_CB; ++c) {
    const float* cbl = cb + (size_t)c * K_NUM * DIM;
    const float* sqwl = sqw + c * K_NUM;
    float sqr[2];
    {
#pragma clang fp contract(off)
#pragma unroll
      for (int j = 0; j < 2; ++j) {
        int row = rg + 16 * j;
        float blk[2];
#pragma unroll
        for (int b = 0; b < 2; ++b) {
          float v0 = resS[SWZ2(row, b * 128 + kg)];
          float acc = v0 * v0;
          for (int i = 1; i < 16; ++i) {
            float v = resS[SWZ2(row, b * 128 + kg + 8 * i)];
            acc = acc + v * v;
          }
          acc = acc + __shfl_xor(acc, 1, 8);
          acc = acc + __shfl_xor(acc, 2, 8);
          acc = acc + __shfl_xor(acc, 4, 8);
          blk[b] = acc;
        }
        sqr[j] = blk[0] + blk[1];
      }
    }
    float m1[2], m2[2]; int i1[2], i2[2];
    m1[0] = m1[1] = m2[0] = m2[1] = FLT_MAX;
    i1[0] = i1[1] = i2[0] = i2[1] = 0x7FFFFFFF;
    for (int tile = 0; tile < K_NUM / 32; ++tile) {
      __syncthreads();
      const float* wsrc = cbl + (size_t)tile * 32 * DIM;
#pragma unroll 4
      for (int it = 0; it < 32; ++it) {
        float2 v = *(const float2*)&wsrc[(size_t)it * DIM + t * 2];
        *(float2*)&Wt[SWZV(it, t)] = v;
      }
      __syncthreads();
      float acc[4][2] = {{0.f, 0.f}, {0.f, 0.f}, {0.f, 0.f}, {0.f, 0.f}};
#pragma unroll 8
      for (int du = 0; du < DIM / 2; ++du) {
        float2 r0 = *(const float2*)&resS[SWZV(rg, du)];
        float2 r1 = *(const float2*)&resS[SWZV(rg + 16, du)];
#pragma unroll
        for (int i = 0; i < 4; ++i) {
          int k = kg + 8 * i;
          float2 w = *(const float2*)&Wt[SWZV(k, du)];
          acc[i][0] += w.x * r0.x; acc[i][0] += w.y * r0.y;
          acc[i][1] += w.x * r1.x; acc[i][1] += w.y * r1.y;
        }
      }
#pragma unroll
      for (int i = 0; i < 4; ++i) {
        int k = tile * 32 + kg + 8 * i;
        float b = sqwl[k];
#pragma unroll
        for (int j = 0; j < 2; ++j) {
          float s = b - 2.0f * acc[i][j];
          if (lexless(s, k, m1[j], i1[j])) {
            m2[j] = m1[j]; i2[j] = i1[j]; m1[j] = s; i1[j] = k;
          } else if (lexless(s, k, m2[j], i2[j])) {
            m2[j] = s; i2[j] = k;
          }
        }
      }
    }
    float as[2][4]; int ak[2][4];
#pragma unroll
    for (int j = 0; j < 2; ++j) {
      as[j][0] = m1[j]; ak[j][0] = i1[j];
      as[j][1] = m2[j]; ak[j][1] = i2[j];
      as[j][2] = FLT_MAX; ak[j][2] = 0x7FFFFFFF;
      as[j][3] = FLT_MAX; ak[j][3] = 0x7FFFFFFF;
#pragma unroll
      for (int off = 1; off <= 4; off <<= 1) {
        float bs[4]; int bk[4];
#pragma unroll
        for (int q = 0; q < 4; ++q) {
          bs[q] = __shfl_xor(as[j][q], off, 8);
          bk[q] = __shfl_xor(ak[j][q], off, 8);
        }
        float cs[4]; int ck[4];
#pragma unroll
        for (int q = 0; q < 4; ++q) {
          bool ta = lexless(as[j][q], ak[j][q], bs[3 - q], bk[3 - q]);
          cs[q] = ta ? as[j][q] : bs[3 - q];
          ck[q] = ta ? ak[j][q] : bk[3 - q];
        }
#define CE(p, q) { bool sw = lexless(cs[q], ck[q], cs[p], ck[p]); \
                   float ts = sw ? cs[q] : cs[p]; int tk = sw ? ck[q] : ck[p]; \
                   cs[q] = sw ? cs[p] : cs[q]; ck[q] = sw ? ck[p] : ck[q]; \
                   cs[p] = ts; ck[p] = tk; }
        CE(0, 2) CE(1, 3) CE(0, 1) CE(2, 3)
#undef CE
#pragma unroll
        for (int q = 0; q < 4; ++q) { as[j][q] = cs[q]; ak[j][q] = ck[q]; }
      }
    }
    int winner[2];
#pragma unroll
    for (int j = 0; j < 2; ++j) {
      if (as[j][1] <= as[j][0] + 1.2e-4f) {
        int row = rg + 16 * j;
        float ss = (kg == 0) ? as[j][0] : (kg == 1) ? as[j][1]
                 : (kg == 2) ? as[j][2] : (kg == 3) ? as[j][3] : FLT_MAX;
        int   sk = (kg == 0) ? ak[j][0] : (kg == 1) ? ak[j][1]
                 : (kg == 2) ? ak[j][2] : (kg == 3) ? ak[j][3] : 0x7FFFFFFF;
        float myd = FLT_MAX; int myk = 0x7FFFFFFF;
        if (kg < 4 && ss <= as[j][0] + 1.2e-4f) {
          const float* wrow = cbl + (size_t)sk * DIM;
          float g = 0.0f;
#pragma unroll 8
          for (int d = 0; d < DIM; ++d)
            g = __builtin_fmaf(wrow[d], resS[SWZ2(row, d)], g);
          float T = sqr[j] + sqwl[sk];
          myd = T - 2.0f * g;
          myk = sk;
        }
#pragma unroll
        for (int off = 1; off <= 4; off <<= 1) {
          float od = __shfl_xor(myd, off, 8);
          int   ok = __shfl_xor(myk, off, 8);
          if (lexless(od, ok, myd, myk)) { myd = od; myk = ok; }
        }
        winner[j] = myk;
      } else {
        winner[j] = ak[j][0];
      }
    }
    __syncthreads();
    int* idxSf = (int*)Wt;
    if (kg == 0) {
      idxSf[rg] = winner[0];
      idxSf[rg + 16] = winner[1];
      out[(size_t)IDXOFF + (size_t)c * N_ROWS + rb + rg] = (float)winner[0];
      out[(size_t)IDXOFF + (size_t)c * N_ROWS + rb + rg + 16] = (float)winner[1];
      atomicAdd(&counts[c * K_NUM + winner[0]], 1);
      atomicAdd(&counts[c * K_NUM + winner[1]], 1);
    }
    __syncthreads();
    double lsse = 0.0;
#pragma unroll 4
    for (int it = 0; it < RPB; ++it) {
      int widx = idxSf[it];
      size_t go = (size_t)(rb + it) * DIM + t * 2;
      float2 wv = *(const float2*)&cbl[(size_t)widx * DIM + t * 2];
      float2 rv = *(const float2*)&resS[SWZV(it, t)];
      float ex = wv.x - rv.x, ey = wv.y - rv.y;
      float qsx = rv.x + ex, qsy = rv.y + ey;
      float qnx, qny;
      if (c == 0) { qnx = qsx; qny = qsy; }
      else { float2 qo = *(const float2*)&out[go]; qnx = qo.x + qsx; qny = qo.y + qsy; }
      *(float2*)&out[go] = make_float2(qnx, qny);
      float2 xv = *(const float2*)&x[go];
      float rnx = xv.x - qnx, rny = xv.y - qny;
      *(float2*)&resS[SWZV(it, t)] = make_float2(rnx, rny);
      lsse += (double)ex * (double)ex + (double)ey * (double)ey;
    }
#pragma unroll
    for (int off = 32; off; off >>= 1) lsse += __shfl_xor(lsse, off, 64);
    if ((t & 63) == 0) atomicAdd(&sse[c], lsse);
    __syncthreads();
  }
}

__global__ void finalize_kernel(const int* __restrict__ counts,
                                const double* __restrict__ sse,
                                const double* __restrict__ pdacc,
                                float* __restrict__ out, double pdscale) {
  __shared__ double red[1024];
  int t = threadIdx.x;
  double u = 0.0;
#pragma unroll
  for (int c = 0; c < 4; ++c) u += fabs((double)counts[c * 1024 + t] - 64.0);
  red[t] = u;
  __syncthreads();
  for (int s = 512; s; s >>= 1) {
    if (t < s) red[t] += red[t + s];
    __syncthreads();
  }
  if (t == 0) {
    double q = 0.0;
#pragma unroll
    for (int c = 0; c < 4; ++c) q += sse[c];
    q *= 1.25 / ((double)N_ROWS * (double)DIM);
    out[QOFF + 0] = (float)q;
    out[QOFF + 1] = (float)(red[0] / 1024.0);
    out[QOFF + 2] = (float)(pdscale * pdacc[0] / (double)NPAIRS);
  }
}

extern "C" void kernel_launch(void* const* d_in, const int* in_sizes, int n_in,
                              void* d_out, int out_size, void* d_ws, size_t ws_size,
                              hipStream_t stream) {
  const float* x  = (const float*)d_in[0];
  const float* cb = (const float*)d_in[1];
  float* out = (float*)d_out;

  char* w = (char*)d_ws;
  double* wn64   = (double*)(w);
  float*  sqw    = (float*) (w + 32768);
  int*    counts = (int*)   (w + 49152);
  double* sse    = (double*)(w + 65536);
  double* pdacc  = (double*)(w + 65568);
  _Float16* bws  = (_Float16*)(w + WS_BWS_OFF);

  zero_ws<<<16, 256, 0, stream>>>(counts, sse, pdacc);
  np_sqw_kernel<<<16, 256, 0, stream>>>(cb, sqw);
  if (ws_size >= WS_NEEDED) {
    cvt_b_kernel<<<512, 256, 0, stream>>>(cb, bws);
    pdist_mfma<<<256, 256, 0, stream>>>(bws, sqw, pdacc);
    rvq_main_mfma<<<N_ROWS / RPB, 256, 0, stream>>>(x, cb, bws, sqw, counts, sse, out);
    finalize_kernel<<<1, 1024, 0, stream>>>(counts, sse, pdacc, out, 1.0);
  } else {
    wnorm_kernel<<<1024, 256, 0, stream>>>(cb, wn64);
    pdist_kernel<<<4096, 128, 0, stream>>>(cb, wn64, pdacc);
    rvq_main_fb<<<N_ROWS / RPB, 128, 0, stream>>>(x, cb, sqw, counts, sse, out);
    finalize_kernel<<<1, 1024, 0, stream>>>(counts, sse, pdacc, out, 2.0);
  }
}

// Round 6
// 974.999 us; speedup vs baseline: 1.1268x; 1.1026x over previous
//
#include <hip/hip_runtime.h>
#include <math.h>
#include <float.h>

// ResidualVectorQuantizer — Round 9: R4 structure + atomics out of barrier regions.
//
// np ref model (verified exact, absmax 0 in R2..R8):
//   G = r @ W.T (sequential-k fmaf), dist = fl(fl(sq_r+sq_w) - fl(2G)),
//   idx = lex-(dist,k) argmin; sq_r/sq_w = numpy pairwise sum (128+128, 8 acc).
// Stage 1 ranks with fp16 MFMA; |np_dist - approx| <= MARGIN; the within-margin
// candidate set is collected exactly and rescored with the exact np formula.
//
// R9 theory (from R6/R7/R8 falsifications): dur is pinned at ~860-980 us while
// traffic varies 2x and occupancy varies 2x => the floor is the same-address
// device-atomic serial chain (32768 f64 atomicAdds on sse[c], 262144 int
// atomicAdds on counts), each drained by the pre-barrier vmcnt(0).
// Single change vs R4 (best, 861 us):
//  * lsse accumulated in-register across ALL levels; ONE wave-reduce at kernel
//    end; 4 atomics/block into sse[0] (finalize sums sse[0..3] -> exact).
//  * winners kept in LDS idxAll[4][32]; idx stores + counts atomics fired in a
//    post-loop epilogue, outside every barrier-drained region.

#define N_ROWS 65536
#define DIM    256
#define K_NUM  1024
#define N_CB   4
#define RPB    32
#define QOFF   16777216     // N_ROWS*DIM
#define IDXOFF 16777219     // QOFF + 3 scalars
#define NPAIRS 523776
#define MARGIN 2.4e-4f

#define SWZV(row, dunit) ((row) * DIM + ((((dunit) ^ ((row) & 7))) << 1))
#define SWZ2(row, d)     ((row) * DIM + ((((((d) >> 1) ^ ((row) & 7))) << 1) | ((d) & 1)))
// Af chunk address (in f16 elements), XOR-swizzled for conflict-free wr/rd
#define AFCH(mt, kk, q, m) \
  (((((mt) * 8 + (kk)) * 64) + (q) * 16 + (((m) ^ ((q) << 1) ^ (kk)) & 15)) * 8)

typedef _Float16 f16x8 __attribute__((ext_vector_type(8)));
typedef float    f32x4 __attribute__((ext_vector_type(4)));

// ---------------- ws layout ----------------
// [0, 32768)        double wn64[4096]      (fallback pdist only)
// [32768, 49152)    float  sqw[4096]       (np-exact ||w||^2)
// [49152, 65536)    int    counts[4096]
// [65536, 65568)    double sse[4]
// [65568, 65576)    double pdacc[1]
// [69632, 2166784)  _Float16 bws[1048576]  (fp16 codebooks, fragment-major)
#define WS_BWS_OFF 69632
#define WS_NEEDED  2166784

__device__ __forceinline__ bool lexless(float a, int ka, float b, int kb) {
  return (a < b) || (a == b && ka < kb);
}

__global__ void zero_ws(int* counts, double* sse, double* pdacc) {
  int t = blockIdx.x * blockDim.x + threadIdx.x;
  if (t < 4096) counts[t] = 0;
  if (t < 4) sse[t] = 0.0;
  if (t == 0) pdacc[0] = 0.0;
}

// np-exact sum(W*W, axis=1): pairwise structure for n=256
__global__ void np_sqw_kernel(const float* __restrict__ cb,
                              float* __restrict__ sqw) {
#pragma clang fp contract(off)
  int g = blockIdx.x * blockDim.x + threadIdx.x;  // 0..4095
  const float* row = cb + (size_t)g * DIM;
  float blk[2];
#pragma unroll
  for (int b = 0; b < 2; ++b) {
    const float* a = row + b * 128;
    float r[8];
#pragma unroll
    for (int j = 0; j < 8; ++j) { float v = a[j]; r[j] = v * v; }
    for (int i = 8; i < 128; i += 8) {
#pragma unroll
      for (int j = 0; j < 8; ++j) { float v = a[i + j]; r[j] = r[j] + v * v; }
    }
    blk[b] = ((r[0] + r[1]) + (r[2] + r[3])) + ((r[4] + r[5]) + (r[6] + r[7]));
  }
  sqw[g] = blk[0] + blk[1];
}

// codebooks -> fp16 fragment-major (global layout is linear, lane*8)
__global__ void cvt_b_kernel(const float* __restrict__ cb,
                             _Float16* __restrict__ bws) {
  int tg = blockIdx.x * blockDim.x + threadIdx.x;  // 131072 threads
  int row = tg >> 5;        // 0..4095
  int chunk = tg & 31;
  int c = row >> 10, n = row & 1023;
  int nt = n >> 4, nin = n & 15;
  int kk = chunk >> 2, quad = chunk & 3;
  const float* src = cb + (size_t)row * DIM + chunk * 8;
  f16x8 h;
#pragma unroll
  for (int j = 0; j < 8; ++j) h[j] = (_Float16)src[j];
  size_t dst = ((size_t)((c * 64 + nt) * 8 + kk) * 64 + quad * 16 + nin) * 8;
  *(f16x8*)(bws + dst) = h;
}

// all-pairs mean distance via fp16 MFMA Gram (precision irrelevant: thr 20.48)
__global__ __launch_bounds__(256) void pdist_mfma(
    const _Float16* __restrict__ bws, const float* __restrict__ sqw,
    double* __restrict__ pdacc) {
  int t = threadIdx.x, lane = t & 63, wq = t >> 6;
  int quad = lane >> 4, col = lane & 15;
  int c = blockIdx.x >> 6, iT = blockIdx.x & 63;
  const float* sq = sqw + c * K_NUM;
  const _Float16* base = bws + ((size_t)(c * 64) * 8) * 512 + lane * 8;
  f16x8 Ar[8];
#pragma unroll
  for (int kk = 0; kk < 8; ++kk)
    Ar[kk] = *(const f16x8*)(base + (size_t)(iT * 8 + kk) * 512);
  float bi[4];
#pragma unroll
  for (int r = 0; r < 4; ++r) bi[r] = sq[iT * 16 + quad * 4 + r];
  float sum = 0.f;
#pragma unroll 1
  for (int jt0 = 0; jt0 < 16; ++jt0) {
    int jt = wq * 16 + jt0;
    f16x8 Br[8];
#pragma unroll
    for (int kk = 0; kk < 8; ++kk)
      Br[kk] = *(const f16x8*)(base + (size_t)(jt * 8 + kk) * 512);
    f32x4 acc = {0.f, 0.f, 0.f, 0.f};
#pragma unroll
    for (int kk = 0; kk < 8; ++kk)
      acc = __builtin_amdgcn_mfma_f32_16x16x32_f16(Ar[kk], Br[kk], acc, 0, 0, 0);
    int j = jt * 16 + col;
    float bj = sq[j];
#pragma unroll
    for (int r = 0; r < 4; ++r) {
      int i = iT * 16 + quad * 4 + r;
      float d2 = bi[r] + bj - 2.0f * acc[r];
      if (i != j) sum += sqrtf(fmaxf(d2, 0.f));
    }
  }
  double ds = (double)sum;
#pragma unroll
  for (int off = 32; off; off >>= 1) ds += __shfl_xor(ds, off, 64);
  if (lane == 0) atomicAdd(pdacc, ds);
}

// ================= MFMA main kernel =================
__global__ __launch_bounds__(256, 3) void rvq_main_mfma(
    const float* __restrict__ x, const float* __restrict__ cb,
    const _Float16* __restrict__ bws, const float* __restrict__ sqw,
    int* __restrict__ counts, double* __restrict__ sse,
    float* __restrict__ out) {
  __shared__ float resS[RPB * DIM];                      // 32 KB, swizzled f32
  __shared__ __align__(16) _Float16 Af[16 * 64 * 8];     // 16 KB, persistent frags
  __shared__ float wminS[RPB * 4];
  __shared__ int hardCnt[RPB];
  __shared__ int hardIdx[RPB * 6];
  __shared__ int idxAll[N_CB][RPB];                      // winners, all levels
  __shared__ float sqrS[RPB];

  int t = threadIdx.x;            // 0..255
  int lane = t & 63, wq = t >> 6;
  int quad = lane >> 4, m16 = lane & 15;
  int rb = blockIdx.x * RPB;
  int dchunk = t & 31, rowgrp = t >> 5;   // update/staging mapping (8d chunks)

  double lsseAll = 0.0;           // SSE accumulated across ALL levels

  // ---- stage: residual = x -> resS (f32) + Af (f16 frags) ----
#pragma unroll
  for (int i = 0; i < 4; ++i) {
    int row = rowgrp * 4 + i;
    size_t go = (size_t)(rb + row) * DIM + dchunk * 8;
    float xv[8];
    *(float4*)&xv[0] = *(const float4*)&x[go];
    *(float4*)&xv[4] = *(const float4*)&x[go + 4];
    f16x8 h;
#pragma unroll
    for (int j = 0; j < 8; ++j) h[j] = (_Float16)xv[j];
    *(f16x8*)(Af + AFCH(row >> 4, dchunk >> 2, dchunk & 3, row & 15)) = h;
    int u0 = dchunk * 4;
    *(float2*)&resS[SWZV(row, u0 + 0)] = make_float2(xv[0], xv[1]);
    *(float2*)&resS[SWZV(row, u0 + 1)] = make_float2(xv[2], xv[3]);
    *(float2*)&resS[SWZV(row, u0 + 2)] = make_float2(xv[4], xv[5]);
    *(float2*)&resS[SWZV(row, u0 + 3)] = make_float2(xv[6], xv[7]);
  }
  __syncthreads();

  for (int c = 0; c < N_CB; ++c) {
    const float* cbl = cb + (size_t)c * K_NUM * DIM;
    const float* sqwl = sqw + c * K_NUM;

    // ---- ph0: np-exact sq_r per row (8-lane pairwise replica) ----
    {
#pragma clang fp contract(off)
      int kg = t & 7, rg = t >> 3;
      float blk[2];
#pragma unroll
      for (int b = 0; b < 2; ++b) {
        float v0 = resS[SWZ2(rg, b * 128 + kg)];
        float acc = v0 * v0;
        for (int i = 1; i < 16; ++i) {
          float v = resS[SWZ2(rg, b * 128 + kg + 8 * i)];
          acc = acc + v * v;
        }
        acc = acc + __shfl_xor(acc, 1, 8);
        acc = acc + __shfl_xor(acc, 2, 8);
        acc = acc + __shfl_xor(acc, 4, 8);
        blk[b] = acc;
      }
      if (kg == 0) sqrS[rg] = blk[0] + blk[1];
    }

    // ---- ph2: MFMA scoring (A hoisted to regs from Af, B streamed from L2) --
    f16x8 Ar[2][8];
#pragma unroll
    for (int kk = 0; kk < 8; ++kk) {
      Ar[0][kk] = *(const f16x8*)(Af + AFCH(0, kk, quad, m16));
      Ar[1][kk] = *(const f16x8*)(Af + AFCH(1, kk, quad, m16));
    }
    float s1[2][4], s2[2][4]; int k1[2][4], k2[2][4];
#pragma unroll
    for (int mt = 0; mt < 2; ++mt)
#pragma unroll
      for (int r = 0; r < 4; ++r) {
        s1[mt][r] = FLT_MAX; s2[mt][r] = FLT_MAX;
        k1[mt][r] = 0x7FFFFFFF; k2[mt][r] = 0x7FFFFFFF;
      }
    const _Float16* Bc = bws + (size_t)((c * 64 + wq * 16) * 8) * 512 + lane * 8;
#pragma unroll 1
    for (int nt = 0; nt < 16; ++nt) {
      const _Float16* Bp = Bc + (size_t)nt * 8 * 512;
      f16x8 Br[8];
#pragma unroll
      for (int kk = 0; kk < 8; ++kk)
        Br[kk] = *(const f16x8*)(Bp + (size_t)kk * 512);
      f32x4 acc0 = {0.f, 0.f, 0.f, 0.f}, acc1 = {0.f, 0.f, 0.f, 0.f};
#pragma unroll
      for (int kk = 0; kk < 8; ++kk) {
        acc0 = __builtin_amdgcn_mfma_f32_16x16x32_f16(Ar[0][kk], Br[kk], acc0, 0, 0, 0);
        acc1 = __builtin_amdgcn_mfma_f32_16x16x32_f16(Ar[1][kk], Br[kk], acc1, 0, 0, 0);
      }
      int n = (wq * 16 + nt) * 16 + m16;
      float w2 = sqwl[n];
#pragma unroll
      for (int r = 0; r < 4; ++r) {
        float sa = w2 - 2.0f * acc0[r];
        if (sa < s1[0][r]) { s2[0][r] = s1[0][r]; k2[0][r] = k1[0][r]; s1[0][r] = sa; k1[0][r] = n; }
        else if (sa < s2[0][r]) { s2[0][r] = sa; k2[0][r] = n; }
        float sb = w2 - 2.0f * acc1[r];
        if (sb < s1[1][r]) { s2[1][r] = s1[1][r]; k2[1][r] = k1[1][r]; s1[1][r] = sb; k1[1][r] = n; }
        else if (sb < s2[1][r]) { s2[1][r] = sb; k2[1][r] = n; }
      }
    }

    // ---- step1: per-wave row-min -> wminS; zero hardCnt ----
    if (t < RPB) hardCnt[t] = 0;
#pragma unroll
    for (int mt = 0; mt < 2; ++mt)
#pragma unroll
      for (int r = 0; r < 4; ++r) {
        float mn = s1[mt][r];
#pragma unroll
        for (int off = 1; off <= 8; off <<= 1)
          mn = fminf(mn, __shfl_xor(mn, off, 16));
        if (m16 == 0) wminS[(mt * 16 + quad * 4 + r) * 4 + wq] = mn;
      }
    __syncthreads();

    // ---- step2: global thr; collect within-margin candidates via LDS atomics
#pragma unroll
    for (int mt = 0; mt < 2; ++mt)
#pragma unroll
      for (int r = 0; r < 4; ++r) {
        int row = mt * 16 + quad * 4 + r;
        float thr = fminf(fminf(wminS[row * 4 + 0], wminS[row * 4 + 1]),
                          fminf(wminS[row * 4 + 2], wminS[row * 4 + 3])) + MARGIN;
        bool c1 = s1[mt][r] <= thr;
        if (c1) {
          bool c2 = s2[mt][r] <= thr;
          int pos = atomicAdd(&hardCnt[row], 1 + (c2 ? 1 : 0));
          if (pos < 6) hardIdx[row * 6 + pos] = k1[mt][r];
          if (c2 && pos + 1 < 6) hardIdx[row * 6 + pos + 1] = k2[mt][r];
        }
      }
    __syncthreads();

    // ---- ph5: winner per row (cnt==1 fast; else exact np rescore) ----
    // winner -> LDS only; global idx stores + counts atomics deferred to epilogue
    {
      int kg = t & 7, rg = t >> 3;
      int cnt = hardCnt[rg]; if (cnt > 6) cnt = 6;
      int winner;
      if (cnt == 1) {
        winner = hardIdx[rg * 6];
      } else {
        float myd = FLT_MAX; int myk = 0x7FFFFFFF;
        if (kg < cnt) {
          int k = hardIdx[rg * 6 + kg];
          const float* wrow = cbl + (size_t)k * DIM;
          float gsum = 0.0f;
#pragma unroll 8
          for (int d = 0; d < DIM; ++d)
            gsum = __builtin_fmaf(wrow[d], resS[SWZ2(rg, d)], gsum);
          float T = sqrS[rg] + sqwl[k];   // fl(sq_r + sq_w)
          myd = T - 2.0f * gsum;          // fl(T - 2g), 2g exact
          myk = k;
        }
#pragma unroll
        for (int off = 1; off <= 4; off <<= 1) {
          float od = __shfl_xor(myd, off, 8);
          int   ok = __shfl_xor(myk, off, 8);
          if (lexless(od, ok, myd, myk)) { myd = od; myk = ok; }
        }
        winner = myk;
      }
      if (kg == 0) idxAll[c][rg] = winner;
    }
    __syncthreads();

    // ---- ph6: exact f32 update chain (R4 verified: x + q round-trip) ----
#pragma unroll
    for (int i = 0; i < 4; ++i) {
      int row = rowgrp * 4 + i;
      int widx = idxAll[c][row];
      size_t go = (size_t)(rb + row) * DIM + dchunk * 8;
      float xv[8], wv[8], qv[8];
      *(float4*)&xv[0] = *(const float4*)&x[go];
      *(float4*)&xv[4] = *(const float4*)&x[go + 4];
      const float* wrow = cbl + (size_t)widx * DIM + dchunk * 8;
      *(float4*)&wv[0] = *(const float4*)&wrow[0];
      *(float4*)&wv[4] = *(const float4*)&wrow[4];
      if (c != 0) {
        *(float4*)&qv[0] = *(const float4*)&out[go];
        *(float4*)&qv[4] = *(const float4*)&out[go + 4];
      }
      f16x8 h;
      float rnv[8];
#pragma unroll
      for (int j = 0; j < 8; ++j) {
        float rv = (c == 0) ? xv[j] : (xv[j] - qv[j]);  // == stored residual, bit-exact
        float e = wv[j] - rv;                            // e = q - r
        float qs = rv + e;                               // q_st
        float qn = (c == 0) ? qs : (qv[j] + qs);         // quantized accum
        qv[j] = qn;
        float rn = xv[j] - qn;                           // next residual
        rnv[j] = rn;
        h[j] = (_Float16)rn;
        lsseAll += (double)e * (double)e;
      }
      *(float4*)&out[go] = *(const float4*)&qv[0];
      *(float4*)&out[go + 4] = *(const float4*)&qv[4];
      *(f16x8*)(Af + AFCH(row >> 4, dchunk >> 2, dchunk & 3, row & 15)) = h;
      int u0 = dchunk * 4;
      *(float2*)&resS[SWZV(row, u0 + 0)] = make_float2(rnv[0], rnv[1]);
      *(float2*)&resS[SWZV(row, u0 + 1)] = make_float2(rnv[2], rnv[3]);
      *(float2*)&resS[SWZV(row, u0 + 2)] = make_float2(rnv[4], rnv[5]);
      *(float2*)&resS[SWZV(row, u0 + 3)] = make_float2(rnv[6], rnv[7]);
    }
    __syncthreads();
  }  // levels

  // ---- epilogue: all global atomics + idx stores, outside barrier regions --
  {
    double ds = lsseAll;
#pragma unroll
    for (int off = 32; off; off >>= 1) ds += __shfl_xor(ds, off, 64);
    if ((t & 63) == 0) atomicAdd(&sse[0], ds);   // finalize sums sse[0..3]
    if (t < RPB) {
#pragma unroll
      for (int c2 = 0; c2 < N_CB; ++c2) {
        int winner = idxAll[c2][t];
        out[(size_t)IDXOFF + (size_t)c2 * N_ROWS + rb + t] = (float)winner;
        atomicAdd(&counts[c2 * K_NUM + winner], 1);
      }
    }
  }
}

// ================= fallback path (small ws): R2 VALU kernels ================
__global__ void wnorm_kernel(const float* __restrict__ cb,
                             double* __restrict__ wn64) {
  int gw = blockIdx.x * 4 + (threadIdx.x >> 6);
  int lane = threadIdx.x & 63;
  const float* row = cb + (size_t)gw * DIM;
  float4 v = *(const float4*)(row + lane * 4);
  double s = (double)v.x * v.x + (double)v.y * v.y +
             (double)v.z * v.z + (double)v.w * v.w;
#pragma unroll
  for (int off = 32; off; off >>= 1) s += __shfl_xor(s, off, 64);
  if (lane == 0) wn64[gw] = s;
}

__global__ void pdist_kernel(const float* __restrict__ cb,
                             const double* __restrict__ wn64,
                             double* __restrict__ pdacc) {
  __shared__ float wi[DIM];
  int c = blockIdx.x >> 10;
  int i = blockIdx.x & 1023;
  int t = threadIdx.x;  // 128
  const float* rowi = cb + ((size_t)c * K_NUM + i) * DIM;
  *(float2*)&wi[t * 2] = *(const float2*)&rowi[t * 2];
  __syncthreads();
  double bi = wn64[c * K_NUM + i];
  double lsum = 0.0;
  for (int j = i + 1 + t; j < K_NUM; j += 128) {
    const float* rowj = cb + ((size_t)c * K_NUM + j) * DIM;
    double dot = 0.0;
#pragma unroll 8
    for (int d = 0; d < DIM; ++d) dot += (double)rowj[d] * (double)wi[d];
    double d2 = bi + wn64[c * K_NUM + j] - 2.0 * dot;
    lsum += sqrt(fmax(d2, 0.0));
  }
#pragma unroll
  for (int off = 32; off; off >>= 1) lsum += __shfl_xor(lsum, off, 64);
  if ((t & 63) == 0) atomicAdd(pdacc, lsum);
}

__global__ __launch_bounds__(128) void rvq_main_fb(
    const float* __restrict__ x, const float* __restrict__ cb,
    const float* __restrict__ sqw,
    int* __restrict__ counts, double* __restrict__ sse,
    float* __restrict__ out) {
  __shared__ float Wt[RPB * DIM];
  __shared__ float resS[RPB * DIM];
  int t = threadIdx.x;
  int kg = t & 7;
  int rg = t >> 3;
  int rb = blockIdx.x * RPB;
#pragma unroll 4
  for (int it = 0; it < RPB; ++it) {
    float2 v = *(const float2*)&x[(size_t)(rb + it) * DIM + t * 2];
    *(float2*)&resS[SWZV(it, t)] = v;
  }
  __syncthreads();
  for (int c = 0; c < N_CB; ++c) {
    const float* cbl = cb + (size_t)c * K_NUM * DIM;
    const float* sqwl = sqw + c * K_NUM;
    float sqr[2];
    {
#pragma clang fp contract(off)
#pragma unroll
      for (int j = 0; j < 2; ++j) {
        int row = rg + 16 * j;
        float blk[2];
#pragma unroll
        for (int b = 0; b < 2; ++b) {
          float v0 = resS[SWZ2(row, b * 128 + kg)];
          float acc = v0 * v0;
          for (int i = 1; i < 16; ++i) {
            float v = resS[SWZ2(row, b * 128 + kg + 8 * i)];
            acc = acc + v * v;
          }
          acc = acc + __shfl_xor(acc, 1, 8);
          acc = acc + __shfl_xor(acc, 2, 8);
          acc = acc + __shfl_xor(acc, 4, 8);
          blk[b] = acc;
        }
        sqr[j] = blk[0] + blk[1];
      }
    }
    float m1[2], m2[2]; int i1[2], i2[2];
    m1[0] = m1[1] = m2[0] = m2[1] = FLT_MAX;
    i1[0] = i1[1] = i2[0] = i2[1] = 0x7FFFFFFF;
    for (int tile = 0; tile < K_NUM / 32; ++tile) {
      __syncthreads();
      const float* wsrc = cbl + (size_t)tile * 32 * DIM;
#pragma unroll 4
      for (int it = 0; it < 32; ++it) {
        float2 v = *(const float2*)&wsrc[(size_t)it * DIM + t * 2];
        *(float2*)&Wt[SWZV(it, t)] = v;
      }
      __syncthreads();
      float acc[4][2] = {{0.f, 0.f}, {0.f, 0.f}, {0.f, 0.f}, {0.f, 0.f}};
#pragma unroll 8
      for (int du = 0; du < DIM / 2; ++du) {
        float2 r0 = *(const float2*)&resS[SWZV(rg, du)];
        float2 r1 = *(const float2*)&resS[SWZV(rg + 16, du)];
#pragma unroll
        for (int i = 0; i < 4; ++i) {
          int k = kg + 8 * i;
          float2 w = *(const float2*)&Wt[SWZV(k, du)];
          acc[i][0] += w.x * r0.x; acc[i][0] += w.y * r0.y;
          acc[i][1] += w.x * r1.x; acc[i][1] += w.y * r1.y;
        }
      }
#pragma unroll
      for (int i = 0; i < 4; ++i) {
        int k = tile * 32 + kg + 8 * i;
        float b = sqwl[k];
#pragma unroll
        for (int j = 0; j < 2; ++j) {
          float s = b - 2.0f * acc[i][j];
          if (lexless(s, k, m1[j], i1[j])) {
            m2[j] = m1[j]; i2[j] = i1[j]; m1[j] = s; i1[j] = k;
          } else if (lexless(s, k, m2[j], i2[j])) {
            m2[j] = s; i2[j] = k;
          }
        }
      }
    }
    float as[2][4]; int ak[2][4];
#pragma unroll
    for (int j = 0; j < 2; ++j) {
      as[j][0] = m1[j]; ak[j][0] = i1[j];
      as[j][1] = m2[j]; ak[j][1] = i2[j];
      as[j][2] = FLT_MAX; ak[j][2] = 0x7FFFFFFF;
      as[j][3] = FLT_MAX; ak[j][3] = 0x7FFFFFFF;
#pragma unroll
      for (int off = 1; off <= 4; off <<= 1) {
        float bs[4]; int bk[4];
#pragma unroll
        for (int q = 0; q < 4; ++q) {
          bs[q] = __shfl_xor(as[j][q], off, 8);
          bk[q] = __shfl_xor(ak[j][q], off, 8);
        }
        float cs[4]; int ck[4];
#pragma unroll
        for (int q = 0; q < 4; ++q) {
          bool ta = lexless(as[j][q], ak[j][q], bs[3 - q], bk[3 - q]);
          cs[q] = ta ? as[j][q] : bs[3 - q];
          ck[q] = ta ? ak[j][q] : bk[3 - q];
        }
#define CE(p, q) { bool sw = lexless(cs[q], ck[q], cs[p], ck[p]); \
                   float ts = sw ? cs[q] : cs[p]; int tk = sw ? ck[q] : ck[p]; \
                   cs[q] = sw ? cs[p] : cs[q]; ck[q] = sw ? ck[p] : ck[q]; \
                   cs[p] = ts; ck[p] = tk; }
        CE(0, 2) CE(1, 3) CE(0, 1) CE(2, 3)
#undef CE
#pragma unroll
        for (int q = 0; q < 4; ++q) { as[j][q] = cs[q]; ak[j][q] = ck[q]; }
      }
    }
    int winner[2];
#pragma unroll
    for (int j = 0; j < 2; ++j) {
      if (as[j][1] <= as[j][0] + 1.2e-4f) {
        int row = rg + 16 * j;
        float ss = (kg == 0) ? as[j][0] : (kg == 1) ? as[j][1]
                 : (kg == 2) ? as[j][2] : (kg == 3) ? as[j][3] : FLT_MAX;
        int   sk = (kg == 0) ? ak[j][0] : (kg == 1) ? ak[j][1]
                 : (kg == 2) ? ak[j][2] : (kg == 3) ? ak[j][3] : 0x7FFFFFFF;
        float myd = FLT_MAX; int myk = 0x7FFFFFFF;
        if (kg < 4 && ss <= as[j][0] + 1.2e-4f) {
          const float* wrow = cbl + (size_t)sk * DIM;
          float g = 0.0f;
#pragma unroll 8
          for (int d = 0; d < DIM; ++d)
            g = __builtin_fmaf(wrow[d], resS[SWZ2(row, d)], g);
          float T = sqr[j] + sqwl[sk];
          myd = T - 2.0f * g;
          myk = sk;
        }
#pragma unroll
        for (int off = 1; off <= 4; off <<= 1) {
          float od = __shfl_xor(myd, off, 8);
          int   ok = __shfl_xor(myk, off, 8);
          if (lexless(od, ok, myd, myk)) { myd = od; myk = ok; }
        }
        winner[j] = myk;
      } else {
        winner[j] = ak[j][0];
      }
    }
    __syncthreads();
    int* idxSf = (int*)Wt;
    if (kg == 0) {
      idxSf[rg] = winner[0];
      idxSf[rg + 16] = winner[1];
      out[(size_t)IDXOFF + (size_t)c * N_ROWS + rb + rg] = (float)winner[0];
      out[(size_t)IDXOFF + (size_t)c * N_ROWS + rb + rg + 16] = (float)winner[1];
      atomicAdd(&counts[c * K_NUM + winner[0]], 1);
      atomicAdd(&counts[c * K_NUM + winner[1]], 1);
    }
    __syncthreads();
    double lsse = 0.0;
#pragma unroll 4
    for (int it = 0; it < RPB; ++it) {
      int widx = idxSf[it];
      size_t go = (size_t)(rb + it) * DIM + t * 2;
      float2 wv = *(const float2*)&cbl[(size_t)widx * DIM + t * 2];
      float2 rv = *(const float2*)&resS[SWZV(it, t)];
      float ex = wv.x - rv.x, ey = wv.y - rv.y;
      float qsx = rv.x + ex, qsy = rv.y + ey;
      float qnx, qny;
      if (c == 0) { qnx = qsx; qny = qsy; }
      else { float2 qo = *(const float2*)&out[go]; qnx = qo.x + qsx; qny = qo.y + qsy; }
      *(float2*)&out[go] = make_float2(qnx, qny);
      float2 xv = *(const float2*)&x[go];
      float rnx = xv.x - qnx, rny = xv.y - qny;
      *(float2*)&resS[SWZV(it, t)] = make_float2(rnx, rny);
      lsse += (double)ex * (double)ex + (double)ey * (double)ey;
    }
#pragma unroll
    for (int off = 32; off; off >>= 1) lsse += __shfl_xor(lsse, off, 64);
    if ((t & 63) == 0) atomicAdd(&sse[c], lsse);
    __syncthreads();
  }
}

__global__ void finalize_kernel(const int* __restrict__ counts,
                                const double* __restrict__ sse,
                                const double* __restrict__ pdacc,
                                float* __restrict__ out, double pdscale) {
  __shared__ double red[1024];
  int t = threadIdx.x;
  double u = 0.0;
#pragma unroll
  for (int c = 0; c < 4; ++c) u += fabs((double)counts[c * 1024 + t] - 64.0);
  red[t] = u;
  __syncthreads();
  for (int s = 512; s; s >>= 1) {
    if (t < s) red[t] += red[t + s];
    __syncthreads();
  }
  if (t == 0) {
    double q = 0.0;
#pragma unroll
    for (int c = 0; c < 4; ++c) q += sse[c];
    q *= 1.25 / ((double)N_ROWS * (double)DIM);
    out[QOFF + 0] = (float)q;
    out[QOFF + 1] = (float)(red[0] / 1024.0);
    out[QOFF + 2] = (float)(pdscale * pdacc[0] / (double)NPAIRS);
  }
}

extern "C" void kernel_launch(void* const* d_in, const int* in_sizes, int n_in,
                              void* d_out, int out_size, void* d_ws, size_t ws_size,
                              hipStream_t stream) {
  const float* x  = (const float*)d_in[0];
  const float* cb = (const float*)d_in[1];
  float* out = (float*)d_out;

  char* w = (char*)d_ws;
  double* wn64   = (double*)(w);
  float*  sqw    = (float*) (w + 32768);
  int*    counts = (int*)   (w + 49152);
  double* sse    = (double*)(w + 65536);
  double* pdacc  = (double*)(w + 65568);
  _Float16* bws  = (_Float16*)(w + WS_BWS_OFF);

  zero_ws<<<16, 256, 0, stream>>>(counts, sse, pdacc);
  np_sqw_kernel<<<16, 256, 0, stream>>>(cb, sqw);
  if (ws_size >= WS_NEEDED) {
    cvt_b_kernel<<<512, 256, 0, stream>>>(cb, bws);
    pdist_mfma<<<256, 256, 0, stream>>>(bws, sqw, pdacc);
    rvq_main_mfma<<<N_ROWS / RPB, 256, 0, stream>>>(x, cb, bws, sqw, counts, sse, out);
    finalize_kernel<<<1, 1024, 0, stream>>>(counts, sse, pdacc, out, 1.0);
  } else {
    wnorm_kernel<<<1024, 256, 0, stream>>>(cb, wn64);
    pdist_kernel<<<4096, 128, 0, stream>>>(cb, wn64, pdacc);
    rvq_main_fb<<<N_ROWS / RPB, 128, 0, stream>>>(x, cb, sqw, counts, sse, out);
    finalize_kernel<<<1, 1024, 0, stream>>>(counts, sse, pdacc, out, 2.0);
  }
}